// Round 1
// baseline (12469.977 us; speedup 1.0000x reference)
//
#include <hip/hip_runtime.h>
#include <hip/hip_bf16.h>

#define B 256
#define T 256
#define M 256
#define P 256
#define TSTEPS 255
#define NT 512

__device__ __forceinline__ float fast_tanh(float x) {
    // tanh(x) = 1 - 2/(exp(2x)+1); clamp to keep exp finite
    x = fminf(fmaxf(x, -15.f), 15.f);
    float e = __expf(2.f * x);
    return 1.f - 2.f * __builtin_amdgcn_rcpf(e + 1.f);
}

__device__ __forceinline__ float sigmoid_acc(float x) {
    return 1.f / (1.f + expf(-x));
}

// ---------------- Ue = encoder_h @ Wu + bu  (65536 x 256, K=256) ----------------
__global__ __launch_bounds__(256) void ue_gemm(
    const float* __restrict__ enc, const float* __restrict__ Wu,
    const float* __restrict__ bu, float* __restrict__ Ue)
{
    __shared__ float At[32][256];   // 32 rows of A, 32 KB
    const int r0 = blockIdx.x * 32;
    const int tid = threadIdx.x;

    #pragma unroll 4
    for (int i = 0; i < 32; ++i)
        At[i][tid] = enc[(size_t)(r0 + i) * 256 + tid];
    __syncthreads();

    float acc[32];
    #pragma unroll
    for (int r = 0; r < 32; ++r) acc[r] = 0.f;

    for (int k = 0; k < 256; k += 4) {
        float w0 = Wu[(size_t)(k + 0) * 256 + tid];
        float w1 = Wu[(size_t)(k + 1) * 256 + tid];
        float w2 = Wu[(size_t)(k + 2) * 256 + tid];
        float w3 = Wu[(size_t)(k + 3) * 256 + tid];
        #pragma unroll
        for (int r = 0; r < 32; ++r) {
            float4 a4 = *(const float4*)&At[r][k];
            acc[r] += a4.x * w0 + a4.y * w1 + a4.z * w2 + a4.w * w3;
        }
    }
    float bub = bu[tid];
    #pragma unroll 4
    for (int r = 0; r < 32; ++r)
        Ue[(size_t)(r0 + r) * 256 + tid] = acc[r] + bub;
}

// ---------------- main scan: one block per batch element ----------------
__global__ __launch_bounds__(NT) void decoder_scan(
    const float* __restrict__ data, const float* __restrict__ enc,
    const float* __restrict__ h0,  const float* __restrict__ s0,
    const float* __restrict__ Wd,  const float* __restrict__ bd,
    const float* __restrict__ Wk,  const float* __restrict__ Wr, const float* __restrict__ bl,
    const float* __restrict__ Ww,  const float* __restrict__ bw,
    const float* __restrict__ Wv,  const float* __restrict__ bv,
    const float* __restrict__ Wvb, const float* __restrict__ bvb,
    const float* __restrict__ Wwb, const float* __restrict__ bwb,
    const float* __restrict__ Ue,
    float* __restrict__ out)
{
    const int b    = blockIdx.x;
    const int tid  = threadIdx.x;
    const int lane = tid & 63;
    const int wave = tid >> 6;      // 0..7

    __shared__ float h_lds[256], s_lds[256], ctx_lds[256];
    __shared__ float z_lds[1024];
    __shared__ float dscp[2][256];
    __shared__ float dsc_lds[256];
    __shared__ float el_lds[256];
    __shared__ float ctxp[2][256];
    __shared__ float wred[8];

    if (tid < 256) {
        h_lds[tid]   = h0[b * 256 + tid];
        s_lds[tid]   = s0[b * 256 + tid];
        ctx_lds[tid] = 0.f;
    }
    __syncthreads();

    const float Wd0 = Wd[0];
    const float bd0 = bd[0];
    const float bv0 = bv[0];
    const int   am  = lane * 4;                         // this lane's 4 m-values
    const float4 wv4 = *(const float4*)&Wv[am];

    const float* UeB  = Ue + (size_t)b * T * M;
    const float* encB = enc + (size_t)b * T * M;
    const float2* Wr2 = (const float2*)Wr;

    for (int t = 0; t < TSTEPS; ++t) {
        // ---- Phase A: y = x_t*Wd0 + <ctx, Wd[1:]> + bd ----
        float yp = (tid < 256) ? ctx_lds[tid] * Wd[1 + tid] : 0.f;
        #pragma unroll
        for (int mm = 32; mm >= 1; mm >>= 1) yp += __shfl_xor(yp, mm, 64);
        if (lane == 0) wred[wave] = yp;
        __syncthreads();
        const float ys = (wred[0] + wred[1] + wred[2] + wred[3])
                       + data[b * TSTEPS + t] * Wd0 + bd0;

        // ---- Phase B: z = y*Wk + h@Wr + bl ; thread owns cols (2tid, 2tid+1) ----
        float accx = 0.f, accy = 0.f;
        #pragma unroll 2
        for (int p = 0; p < 256; p += 4) {
            float4 h4 = *(const float4*)&h_lds[p];
            float2 w0 = Wr2[(size_t)(p + 0) * 512 + tid];
            float2 w1 = Wr2[(size_t)(p + 1) * 512 + tid];
            float2 w2 = Wr2[(size_t)(p + 2) * 512 + tid];
            float2 w3 = Wr2[(size_t)(p + 3) * 512 + tid];
            accx += h4.x * w0.x + h4.y * w1.x + h4.z * w2.x + h4.w * w3.x;
            accy += h4.x * w0.y + h4.y * w1.y + h4.z * w2.y + h4.w * w3.y;
        }
        {
            float2 wk = ((const float2*)Wk)[tid];
            float2 b2 = ((const float2*)bl)[tid];
            accx += ys * wk.x + b2.x;
            accy += ys * wk.y + b2.y;
        }
        z_lds[2 * tid]     = accx;
        z_lds[2 * tid + 1] = accy;
        __syncthreads();

        // ---- Phase C: LSTM gates (i,f,g,o) ----
        if (tid < 256) {
            float zi = z_lds[tid];
            float zf = z_lds[256 + tid];
            float zg = z_lds[512 + tid];
            float zo = z_lds[768 + tid];
            float sn = sigmoid_acc(zf) * s_lds[tid] + sigmoid_acc(zi) * tanhf(zg);
            float hn = sigmoid_acc(zo) * tanhf(sn);
            s_lds[tid] = sn;
            h_lds[tid] = hn;
        }
        __syncthreads();

        // ---- Phase D: dsc = [h,s] @ Ww + bw ; K split over halves ----
        {
            const int m = tid & 255, half = tid >> 8;
            const float* cat = half ? s_lds : h_lds;
            const float* Wwh = Ww + (size_t)half * 256 * 256 + m;
            float a = 0.f;
            #pragma unroll 2
            for (int k = 0; k < 256; k += 4) {
                float4 c4 = *(const float4*)&cat[k];
                a += c4.x * Wwh[(size_t)(k + 0) * 256]
                   + c4.y * Wwh[(size_t)(k + 1) * 256]
                   + c4.z * Wwh[(size_t)(k + 2) * 256]
                   + c4.w * Wwh[(size_t)(k + 3) * 256];
            }
            dscp[half][m] = a;
        }
        __syncthreads();
        if (tid < 256) dsc_lds[tid] = dscp[0][tid] + dscp[1][tid] + bw[tid];
        __syncthreads();

        // ---- Phase E: scores l[t'] = <tanh(dsc + Ue[t']), Wv> + bv, then softmax ----
        {
            const float4 dv = *(const float4*)&dsc_lds[am];
            #pragma unroll 4
            for (int q = 0; q < 32; ++q) {
                const int tp = wave * 32 + q;
                float4 u4 = *(const float4*)&UeB[(size_t)tp * 256 + am];
                float pl = fast_tanh(dv.x + u4.x) * wv4.x
                         + fast_tanh(dv.y + u4.y) * wv4.y
                         + fast_tanh(dv.z + u4.z) * wv4.z
                         + fast_tanh(dv.w + u4.w) * wv4.w;
                #pragma unroll
                for (int mm = 32; mm >= 1; mm >>= 1) pl += __shfl_xor(pl, mm, 64);
                if (lane == 0) el_lds[tp] = pl + bv0;
            }
        }
        __syncthreads();
        float lv = (tid < 256) ? el_lds[tid] : -1e30f;
        float mv = lv;
        #pragma unroll
        for (int mm = 32; mm >= 1; mm >>= 1) mv = fmaxf(mv, __shfl_xor(mv, mm, 64));
        if (lane == 0) wred[wave] = mv;
        __syncthreads();
        const float mx = fmaxf(fmaxf(wred[0], wred[1]), fmaxf(wred[2], wred[3]));
        float ev = (tid < 256) ? expf(lv - mx) : 0.f;
        if (tid < 256) el_lds[tid] = ev;
        float sv = ev;
        #pragma unroll
        for (int mm = 32; mm >= 1; mm >>= 1) sv += __shfl_xor(sv, mm, 64);
        __syncthreads();               // protect wred rewrite + el_lds visibility
        if (lane == 0) wred[wave] = sv;
        __syncthreads();
        const float rS = 1.f / (wred[0] + wred[1] + wred[2] + wred[3]);

        // ---- Phase F: ctx = (sum_t e_t * enc[t,:]) * rS ----
        {
            const int m = tid & 255, half = tid >> 8;
            const float* eB = encB + m;
            float a = 0.f;
            #pragma unroll 2
            for (int q = 0; q < 128; q += 4) {
                const int tp = half * 128 + q;
                float4 e4 = *(const float4*)&el_lds[tp];
                a += e4.x * eB[(size_t)(tp + 0) * 256]
                   + e4.y * eB[(size_t)(tp + 1) * 256]
                   + e4.z * eB[(size_t)(tp + 2) * 256]
                   + e4.w * eB[(size_t)(tp + 3) * 256];
            }
            ctxp[half][m] = a;
        }
        __syncthreads();
        if (tid < 256) ctx_lds[tid] = (ctxp[0][tid] + ctxp[1][tid]) * rS;
        __syncthreads();
    }

    // ---- epilogue: out[b,p] = (<[h,ctx], Wvb> + bvb) * Wwb[p] + bwb[p] ----
    float qp = (tid < 256) ? (h_lds[tid] * Wvb[tid] + ctx_lds[tid] * Wvb[256 + tid]) : 0.f;
    #pragma unroll
    for (int mm = 32; mm >= 1; mm >>= 1) qp += __shfl_xor(qp, mm, 64);
    if (lane == 0) wred[wave] = qp;
    __syncthreads();
    if (tid < 256) {
        float qv = wred[0] + wred[1] + wred[2] + wred[3] + bvb[0];
        out[b * 256 + tid] = qv * Wwb[tid] + bwb[tid];
    }
}

extern "C" void kernel_launch(void* const* d_in, const int* in_sizes, int n_in,
                              void* d_out, int out_size, void* d_ws, size_t ws_size,
                              hipStream_t stream) {
    const float* data = (const float*)d_in[0];
    const float* enc  = (const float*)d_in[1];
    const float* h0   = (const float*)d_in[2];
    const float* s0   = (const float*)d_in[3];
    const float* Wd   = (const float*)d_in[4];
    const float* bd   = (const float*)d_in[5];
    const float* Wk   = (const float*)d_in[6];
    const float* Wr   = (const float*)d_in[7];
    const float* bl   = (const float*)d_in[8];
    const float* Ww   = (const float*)d_in[9];
    const float* bw   = (const float*)d_in[10];
    const float* Wu   = (const float*)d_in[11];
    const float* bu   = (const float*)d_in[12];
    const float* Wv   = (const float*)d_in[13];
    const float* bv   = (const float*)d_in[14];
    const float* Wvb  = (const float*)d_in[15];
    const float* bvb  = (const float*)d_in[16];
    const float* Wwb  = (const float*)d_in[17];
    const float* bwb  = (const float*)d_in[18];

    float* Ue  = (float*)d_ws;          // 64 MB scratch: (B*T, M) fp32
    float* out = (float*)d_out;

    hipLaunchKernelGGL(ue_gemm, dim3((B * T) / 32), dim3(256), 0, stream,
                       enc, Wu, bu, Ue);
    hipLaunchKernelGGL(decoder_scan, dim3(B), dim3(NT), 0, stream,
                       data, enc, h0, s0, Wd, bd, Wk, Wr, bl, Ww, bw,
                       Wv, bv, Wvb, bvb, Wwb, bwb, Ue, out);
}

// Round 2
// 9339.895 us; speedup vs baseline: 1.3351x; 1.3351x over previous
//
#include <hip/hip_runtime.h>
#include <hip/hip_bf16.h>

#define B 256
#define T 256
#define M 256
#define P 256
#define TSTEPS 255
#define NT 512

typedef unsigned int uint;
typedef unsigned short ushort;

__device__ __forceinline__ float bf_lo(uint u) { return __uint_as_float(u << 16); }
__device__ __forceinline__ float bf_hi(uint u) { return __uint_as_float(u & 0xffff0000u); }

__device__ __forceinline__ ushort f2bf(float x) {
    __hip_bfloat16 h = __float2bfloat16(x);
    return *reinterpret_cast<ushort*>(&h);
}

// attention-path tanh: exp handles +-inf gracefully (no clamp needed)
__device__ __forceinline__ float fast_tanh(float x) {
    float e = exp2f(x * 2.88539008f);              // exp(2x)
    return 1.f - 2.f * __builtin_amdgcn_rcpf(e + 1.f);
}

__device__ __forceinline__ float sigmoid_acc(float x) {
    return 1.f / (1.f + expf(-x));
}

// ---------------- Ue16 = bf16(encoder_h @ Wu + bu) ----------------
__global__ __launch_bounds__(256) void ue_gemm(
    const float* __restrict__ enc, const float* __restrict__ Wu,
    const float* __restrict__ bu, ushort* __restrict__ Ue16)
{
    __shared__ float At[32][256];
    const int r0 = blockIdx.x * 32;
    const int tid = threadIdx.x;

    #pragma unroll 4
    for (int i = 0; i < 32; ++i)
        At[i][tid] = enc[(size_t)(r0 + i) * 256 + tid];
    __syncthreads();

    float acc[32];
    #pragma unroll
    for (int r = 0; r < 32; ++r) acc[r] = 0.f;

    for (int k = 0; k < 256; k += 4) {
        float w0 = Wu[(size_t)(k + 0) * 256 + tid];
        float w1 = Wu[(size_t)(k + 1) * 256 + tid];
        float w2 = Wu[(size_t)(k + 2) * 256 + tid];
        float w3 = Wu[(size_t)(k + 3) * 256 + tid];
        #pragma unroll
        for (int r = 0; r < 32; ++r) {
            float4 a4 = *(const float4*)&At[r][k];
            acc[r] += a4.x * w0 + a4.y * w1 + a4.z * w2 + a4.w * w3;
        }
    }
    float bub = bu[tid];
    #pragma unroll 4
    for (int r = 0; r < 32; ++r)
        Ue16[(size_t)(r0 + r) * 256 + tid] = f2bf(acc[r] + bub);
}

// ---------------- enc16 = bf16(encoder_h), packed pairs ----------------
__global__ __launch_bounds__(256) void enc_cvt(
    const float4* __restrict__ in, uint2* __restrict__ out)
{
    int i = blockIdx.x * 256 + threadIdx.x;        // 4,194,304 float4s
    float4 v = in[i];
    uint a = ((uint)f2bf(v.y) << 16) | f2bf(v.x);
    uint b2 = ((uint)f2bf(v.w) << 16) | f2bf(v.z);
    out[i] = make_uint2(a, b2);
}

// ---------------- WwT16[m][kk] = bf16(Ww[kk][m]), kk = half*256+k ----------------
__global__ __launch_bounds__(256) void ww_cvt(
    const float* __restrict__ Ww, ushort* __restrict__ WwT)
{
    int i = blockIdx.x * 256 + threadIdx.x;        // 512*256
    int kk = i >> 8, m = i & 255;
    WwT[(size_t)m * 512 + kk] = f2bf(Ww[i]);
}

// ---------------- main scan: one block per batch element ----------------
template<int WW16>
__global__ __launch_bounds__(NT, 1) void decoder_scan(
    const float* __restrict__ data,
    const float* __restrict__ h0,  const float* __restrict__ s0,
    const float* __restrict__ Wd,  const float* __restrict__ bd,
    const float* __restrict__ Wk,  const float* __restrict__ Wr, const float* __restrict__ bl,
    const float* __restrict__ Ww,  const ushort* __restrict__ WwT16,
    const float* __restrict__ bw,
    const float* __restrict__ Wv,  const float* __restrict__ bv,
    const float* __restrict__ Wvb, const float* __restrict__ bvb,
    const float* __restrict__ Wwb, const float* __restrict__ bwb,
    const ushort* __restrict__ Ue16g, const ushort* __restrict__ enc16g,
    float* __restrict__ out)
{
    const int b    = blockIdx.x;
    const int tid  = threadIdx.x;
    const int lane = tid & 63;
    const int wave = tid >> 6;          // 0..7
    const int ml   = lane & 31;         // m-slot within half-wave
    const int hl   = lane >> 5;         // 0/1

    __shared__ ushort ue16[T * M];      // 128 KB, resident bf16 Ue slice
    __shared__ float h_lds[P], s_lds[P], ctx_lds[M];
    __shared__ float z_lds[4 * P];
    __shared__ float dscp[2][M];
    __shared__ float el_lds[T];
    __shared__ float ctxp[8][M];
    __shared__ float wred[8];

    // ---- stage Ue16 slice into LDS (8192 uint4 = 128KB) ----
    {
        const uint4* src = (const uint4*)(Ue16g + (size_t)b * T * M);
        uint4* dst = (uint4*)ue16;
        #pragma unroll 4
        for (int i = tid; i < 8192; i += NT) dst[i] = src[i];
    }
    if (tid < 256) {
        h_lds[tid]   = h0[b * 256 + tid];
        s_lds[tid]   = s0[b * 256 + tid];
        ctx_lds[tid] = 0.f;
    }
    __syncthreads();

    // ---- hoisted per-thread constants ----
    const float Wd0 = Wd[0];
    const float bd0 = bd[0];
    const float bv0 = bv[0];
    const float wd1 = (tid < 256) ? Wd[1 + tid] : 0.f;
    const float2 wk2 = ((const float2*)Wk)[tid];
    const float2 bl2 = ((const float2*)bl)[tid];
    float wv8[8], bw8[8];
    #pragma unroll
    for (int j = 0; j < 8; ++j) {
        wv8[j] = Wv[ml * 8 + j];
        bw8[j] = bw[ml * 8 + j];
    }

    const uint2* encB4 = (const uint2*)(enc16g + (size_t)b * T * M);
    const float2* Wr2  = (const float2*)Wr;
    const int quad = tid & 63;

    for (int t = 0; t < TSTEPS; ++t) {
        // ---- Phase A: y = x_t*Wd0 + <ctx, Wd[1:]> + bd ----
        float yp = (tid < 256) ? ctx_lds[tid] * wd1 : 0.f;
        #pragma unroll
        for (int mm = 32; mm >= 1; mm >>= 1) yp += __shfl_xor(yp, mm, 64);
        if (lane == 0) wred[wave] = yp;
        __syncthreads();                                       // (1)
        const float ys = (wred[0] + wred[1] + wred[2] + wred[3])
                       + data[b * TSTEPS + t] * Wd0 + bd0;

        // ---- Phase B: z = y*Wk + h@Wr + bl ; thread owns cols (2tid, 2tid+1) ----
        float accx = 0.f, accy = 0.f;
        #pragma unroll 2
        for (int p = 0; p < 256; p += 4) {
            float4 h4 = *(const float4*)&h_lds[p];
            float2 w0 = Wr2[(size_t)(p + 0) * 512 + tid];
            float2 w1 = Wr2[(size_t)(p + 1) * 512 + tid];
            float2 w2 = Wr2[(size_t)(p + 2) * 512 + tid];
            float2 w3 = Wr2[(size_t)(p + 3) * 512 + tid];
            accx += h4.x * w0.x + h4.y * w1.x + h4.z * w2.x + h4.w * w3.x;
            accy += h4.x * w0.y + h4.y * w1.y + h4.z * w2.y + h4.w * w3.y;
        }
        z_lds[2 * tid]     = accx + ys * wk2.x + bl2.x;
        z_lds[2 * tid + 1] = accy + ys * wk2.y + bl2.y;
        __syncthreads();                                       // (2)

        // ---- Phase C: LSTM gates (i,f,g,o) — keep libm precision ----
        if (tid < 256) {
            float zi = z_lds[tid];
            float zf = z_lds[256 + tid];
            float zg = z_lds[512 + tid];
            float zo = z_lds[768 + tid];
            float sn = sigmoid_acc(zf) * s_lds[tid] + sigmoid_acc(zi) * tanhf(zg);
            float hn = sigmoid_acc(zo) * tanhf(sn);
            s_lds[tid] = sn;
            h_lds[tid] = hn;
        }
        __syncthreads();                                       // (3)

        // ---- Phase D: dscp[half][m] = <cat_half, Ww[half][:,m]> ----
        {
            const int m = tid & 255, half = tid >> 8;
            const float* cat = half ? s_lds : h_lds;
            float a = 0.f;
            if (WW16) {
                const uint4* wrow = (const uint4*)(WwT16 + (size_t)m * 512 + half * 256);
                #pragma unroll 4
                for (int kk = 0; kk < 32; ++kk) {
                    uint4 u = wrow[kk];
                    float4 c0 = *(const float4*)&cat[kk * 8];
                    float4 c1 = *(const float4*)&cat[kk * 8 + 4];
                    a += c0.x * bf_lo(u.x) + c0.y * bf_hi(u.x)
                       + c0.z * bf_lo(u.y) + c0.w * bf_hi(u.y)
                       + c1.x * bf_lo(u.z) + c1.y * bf_hi(u.z)
                       + c1.z * bf_lo(u.w) + c1.w * bf_hi(u.w);
                }
            } else {
                const float* Wwh = Ww + (size_t)half * 256 * 256 + m;
                #pragma unroll 2
                for (int k = 0; k < 256; k += 4) {
                    float4 c4 = *(const float4*)&cat[k];
                    a += c4.x * Wwh[(size_t)(k + 0) * 256]
                       + c4.y * Wwh[(size_t)(k + 1) * 256]
                       + c4.z * Wwh[(size_t)(k + 2) * 256]
                       + c4.w * Wwh[(size_t)(k + 3) * 256];
                }
            }
            dscp[half][tid & 255] = a;
        }
        __syncthreads();                                       // (4)

        // ---- Phase E: el[t'] = exp(<tanh(dsc + Ue[t']), Wv> + bv) from LDS ----
        {
            float dsc8[8];
            #pragma unroll
            for (int j = 0; j < 8; ++j)
                dsc8[j] = dscp[0][ml * 8 + j] + dscp[1][ml * 8 + j] + bw8[j];

            float sum_ev = 0.f;
            #pragma unroll 4
            for (int q = 0; q < 16; ++q) {
                const int tp = wave * 32 + 2 * q + hl;
                uint4 u = *(const uint4*)&ue16[tp * 256 + ml * 8];
                float pl;
                pl  = fast_tanh(dsc8[0] + bf_lo(u.x)) * wv8[0];
                pl += fast_tanh(dsc8[1] + bf_hi(u.x)) * wv8[1];
                pl += fast_tanh(dsc8[2] + bf_lo(u.y)) * wv8[2];
                pl += fast_tanh(dsc8[3] + bf_hi(u.y)) * wv8[3];
                pl += fast_tanh(dsc8[4] + bf_lo(u.z)) * wv8[4];
                pl += fast_tanh(dsc8[5] + bf_hi(u.z)) * wv8[5];
                pl += fast_tanh(dsc8[6] + bf_lo(u.w)) * wv8[6];
                pl += fast_tanh(dsc8[7] + bf_hi(u.w)) * wv8[7];
                #pragma unroll
                for (int mm = 16; mm >= 1; mm >>= 1) pl += __shfl_xor(pl, mm, 64);
                if (ml == 0) {   // lanes 0 and 32 hold the two rows' sums
                    float ev = exp2f((pl + bv0) * 1.44269504f);
                    el_lds[tp] = ev;
                    sum_ev += ev;
                }
            }
            #pragma unroll
            for (int mm = 32; mm >= 1; mm >>= 1) sum_ev += __shfl_xor(sum_ev, mm, 64);
            if (lane == 0) wred[wave] = sum_ev;
        }
        __syncthreads();                                       // (5)

        // ---- Phase F: ctx partials from bf16 enc stream ----
        {
            float a0 = 0.f, a1 = 0.f, a2 = 0.f, a3 = 0.f;
            #pragma unroll 4
            for (int i = 0; i < 32; ++i) {
                const int tp = wave * 32 + i;
                float w = el_lds[tp];
                uint2 u = encB4[tp * 64 + quad];
                a0 += w * bf_lo(u.x); a1 += w * bf_hi(u.x);
                a2 += w * bf_lo(u.y); a3 += w * bf_hi(u.y);
            }
            *(float4*)&ctxp[wave][quad * 4] = make_float4(a0, a1, a2, a3);
        }
        __syncthreads();                                       // (6)
        if (tid < 256) {
            float S = wred[0] + wred[1] + wred[2] + wred[3]
                    + wred[4] + wred[5] + wred[6] + wred[7];
            float c = ctxp[0][tid] + ctxp[1][tid] + ctxp[2][tid] + ctxp[3][tid]
                    + ctxp[4][tid] + ctxp[5][tid] + ctxp[6][tid] + ctxp[7][tid];
            ctx_lds[tid] = c / S;
        }
        __syncthreads();                                       // (7)
    }

    // ---- epilogue: out[b,p] = (<[h,ctx], Wvb> + bvb) * Wwb[p] + bwb[p] ----
    float qp = (tid < 256) ? (h_lds[tid] * Wvb[tid] + ctx_lds[tid] * Wvb[256 + tid]) : 0.f;
    #pragma unroll
    for (int mm = 32; mm >= 1; mm >>= 1) qp += __shfl_xor(qp, mm, 64);
    if (lane == 0) wred[wave] = qp;
    __syncthreads();
    if (tid < 256) {
        float qv = wred[0] + wred[1] + wred[2] + wred[3] + bvb[0];
        out[b * 256 + tid] = qv * Wwb[tid] + bwb[tid];
    }
}

extern "C" void kernel_launch(void* const* d_in, const int* in_sizes, int n_in,
                              void* d_out, int out_size, void* d_ws, size_t ws_size,
                              hipStream_t stream) {
    const float* data = (const float*)d_in[0];
    const float* enc  = (const float*)d_in[1];
    const float* h0   = (const float*)d_in[2];
    const float* s0   = (const float*)d_in[3];
    const float* Wd   = (const float*)d_in[4];
    const float* bd   = (const float*)d_in[5];
    const float* Wk   = (const float*)d_in[6];
    const float* Wr   = (const float*)d_in[7];
    const float* bl   = (const float*)d_in[8];
    const float* Ww   = (const float*)d_in[9];
    const float* bw   = (const float*)d_in[10];
    const float* Wu   = (const float*)d_in[11];
    const float* bu   = (const float*)d_in[12];
    const float* Wv   = (const float*)d_in[13];
    const float* bv   = (const float*)d_in[14];
    const float* Wvb  = (const float*)d_in[15];
    const float* bvb  = (const float*)d_in[16];
    const float* Wwb  = (const float*)d_in[17];
    const float* bwb  = (const float*)d_in[18];

    ushort* Ue16  = (ushort*)d_ws;                                   // 32 MB
    ushort* enc16 = (ushort*)((char*)d_ws + (32ull << 20));          // 32 MB
    ushort* WwT16 = (ushort*)((char*)d_ws + (64ull << 20));          // 256 KB
    const bool ww16 = ws_size >= (64ull << 20) + 512 * 256 * 2;
    float* out = (float*)d_out;

    hipLaunchKernelGGL(ue_gemm, dim3((B * T) / 32), dim3(256), 0, stream,
                       enc, Wu, bu, Ue16);
    hipLaunchKernelGGL(enc_cvt, dim3((B * T * M / 4) / 256), dim3(256), 0, stream,
                       (const float4*)enc, (uint2*)enc16);
    if (ww16) {
        hipLaunchKernelGGL(ww_cvt, dim3(512), dim3(256), 0, stream, Ww, WwT16);
        hipLaunchKernelGGL(decoder_scan<1>, dim3(B), dim3(NT), 0, stream,
                           data, h0, s0, Wd, bd, Wk, Wr, bl, Ww, WwT16, bw,
                           Wv, bv, Wvb, bvb, Wwb, bwb, Ue16, enc16, out);
    } else {
        hipLaunchKernelGGL(decoder_scan<0>, dim3(B), dim3(NT), 0, stream,
                           data, h0, s0, Wd, bd, Wk, Wr, bl, Ww, WwT16, bw,
                           Wv, bv, Wvb, bvb, Wwb, bwb, Ue16, enc16, out);
    }
}

// Round 3
// 8639.403 us; speedup vs baseline: 1.4434x; 1.0811x over previous
//
#include <hip/hip_runtime.h>
#include <hip/hip_bf16.h>

#define B 256
#define T 256
#define M 256
#define P 256
#define TSTEPS 255
#define NT 1024

typedef unsigned int uint;
typedef unsigned short ushort;

__device__ __forceinline__ float bf_lo(uint u) { return __uint_as_float(u << 16); }
__device__ __forceinline__ float bf_hi(uint u) { return __uint_as_float(u & 0xffff0000u); }

__device__ __forceinline__ ushort f2bf(float x) {
    __hip_bfloat16 h = __float2bfloat16(x);
    return *reinterpret_cast<ushort*>(&h);
}

__device__ __forceinline__ float fast_tanh(float x) {
    float e = exp2f(x * 2.88539008f);              // exp(2x)
    return 1.f - 2.f * __builtin_amdgcn_rcpf(e + 1.f);
}

__device__ __forceinline__ float sigmoid_acc(float x) {
    return 1.f / (1.f + expf(-x));
}

// ---------------- Ue16 = bf16(encoder_h @ Wu + bu) ----------------
__global__ __launch_bounds__(256) void ue_gemm(
    const float* __restrict__ enc, const float* __restrict__ Wu,
    const float* __restrict__ bu, ushort* __restrict__ Ue16)
{
    __shared__ float At[32][256];
    const int r0 = blockIdx.x * 32;
    const int tid = threadIdx.x;

    #pragma unroll 4
    for (int i = 0; i < 32; ++i)
        At[i][tid] = enc[(size_t)(r0 + i) * 256 + tid];
    __syncthreads();

    float acc[32];
    #pragma unroll
    for (int r = 0; r < 32; ++r) acc[r] = 0.f;

    for (int k = 0; k < 256; k += 4) {
        float w0 = Wu[(size_t)(k + 0) * 256 + tid];
        float w1 = Wu[(size_t)(k + 1) * 256 + tid];
        float w2 = Wu[(size_t)(k + 2) * 256 + tid];
        float w3 = Wu[(size_t)(k + 3) * 256 + tid];
        #pragma unroll
        for (int r = 0; r < 32; ++r) {
            float4 a4 = *(const float4*)&At[r][k];
            acc[r] += a4.x * w0 + a4.y * w1 + a4.z * w2 + a4.w * w3;
        }
    }
    float bub = bu[tid];
    #pragma unroll 4
    for (int r = 0; r < 32; ++r)
        Ue16[(size_t)(r0 + r) * 256 + tid] = f2bf(acc[r] + bub);
}

// ---------------- enc16 = bf16(encoder_h), packed pairs ----------------
__global__ __launch_bounds__(256) void enc_cvt(
    const float4* __restrict__ in, uint2* __restrict__ out)
{
    int i = blockIdx.x * 256 + threadIdx.x;
    float4 v = in[i];
    uint a  = ((uint)f2bf(v.y) << 16) | f2bf(v.x);
    uint b2 = ((uint)f2bf(v.w) << 16) | f2bf(v.z);
    out[i] = make_uint2(a, b2);
}

// ---- Wsz[kc][c][8] = bf16(Wr[kc*8+j][c]) : wave-contiguous 16B chunks ----
__global__ __launch_bounds__(256) void wr_cvt(
    const float* __restrict__ Wr, ushort* __restrict__ Wsz)
{
    int i = blockIdx.x * 256 + threadIdx.x;       // 32768 = kc*1024 + c
    int kc = i >> 10, c = i & 1023;
    ushort tmp[8];
    #pragma unroll
    for (int j = 0; j < 8; ++j)
        tmp[j] = f2bf(Wr[(size_t)(kc * 8 + j) * 1024 + c]);
    *(uint4*)&Wsz[(size_t)i * 8] = *(const uint4*)tmp;
}

// ---- Wwsz[kc][m][8] = bf16(Ww[kc*8+j][m]) ----
__global__ __launch_bounds__(256) void ww_cvt(
    const float* __restrict__ Ww, ushort* __restrict__ Wwsz)
{
    int i = blockIdx.x * 256 + threadIdx.x;       // 16384 = kc*256 + m
    int kc = i >> 8, m = i & 255;
    ushort tmp[8];
    #pragma unroll
    for (int j = 0; j < 8; ++j)
        tmp[j] = f2bf(Ww[(size_t)(kc * 8 + j) * 256 + m]);
    *(uint4*)&Wwsz[(size_t)i * 8] = *(const uint4*)tmp;
}

// ---------------- main scan: one block (1024 thr) per batch element ----------------
template<int FAST>
__global__ __launch_bounds__(NT, 4) void decoder_scan(
    const float* __restrict__ data,
    const float* __restrict__ h0,  const float* __restrict__ s0,
    const float* __restrict__ Wd,  const float* __restrict__ bd,
    const float* __restrict__ Wk,  const float* __restrict__ Wr, const float* __restrict__ bl,
    const float* __restrict__ Ww,  const float* __restrict__ bw,
    const float* __restrict__ Wv,  const float* __restrict__ bv,
    const float* __restrict__ Wvb, const float* __restrict__ bvb,
    const float* __restrict__ Wwb, const float* __restrict__ bwb,
    const ushort* __restrict__ Ue16g, const ushort* __restrict__ enc16g,
    const ushort* __restrict__ Wsz,   const ushort* __restrict__ Wwsz,
    float* __restrict__ out)
{
    const int b    = blockIdx.x;
    const int tid  = threadIdx.x;
    const int lane = tid & 63;
    const int wave = tid >> 6;          // 0..15
    const int ml   = lane & 31;
    const int hl   = lane >> 5;

    __shared__ float h_lds[P], s_lds[P];
    __shared__ float z_lds[4 * P];
    __shared__ float dscp[4][M];
    __shared__ float el_lds[T];
    __shared__ float ctxp[16][M];
    __shared__ float sred[16];
    __shared__ float ya[4];
    __shared__ float data_lds[TSTEPS + 1];

    // ---- init ----
    if (tid < 256) { h_lds[tid] = h0[b * 256 + tid]; s_lds[tid] = s0[b * 256 + tid]; }
    if (tid < 16) sred[tid] = 1.f;      // t=0: S=16, ctxp=0 -> ctx contribution 0
    #pragma unroll
    for (int i = tid; i < 16 * 256; i += NT) ((float*)ctxp)[i] = 0.f;
    if (tid < TSTEPS) data_lds[tid] = data[b * TSTEPS + tid];

    // ---- Ue slice into registers: row = wave*16+2q+hl, cols ml*8..+7 ----
    uint4 ue[8];
    {
        const uint4* ueb = (const uint4*)(Ue16g + (size_t)b * T * M);
        #pragma unroll
        for (int q = 0; q < 8; ++q)
            ue[q] = ueb[(wave * 16 + 2 * q + hl) * 32 + ml];
    }

    // ---- hoisted constants ----
    const float Wd0 = Wd[0], bd0 = bd[0], bv0 = bv[0];
    const float wd1 = (tid < 256) ? Wd[1 + tid] : 0.f;
    const float wkc = Wk[tid], blc = bl[tid];
    float wv8[8], bw8[8];
    #pragma unroll
    for (int j = 0; j < 8; ++j) { wv8[j] = Wv[ml * 8 + j]; bw8[j] = bw[ml * 8 + j]; }

    const uint2* encB = (const uint2*)(enc16g + (size_t)b * T * M);
    __syncthreads();

    for (int t = 0; t < TSTEPS; ++t) {
        // ---- A: y partials from raw ctx partials (normalization folded in later) ----
        if (wave < 4) {
            float yp = 0.f;
            if (tid < 256) {
                float c = 0.f;
                #pragma unroll
                for (int w = 0; w < 16; ++w) c += ctxp[w][tid];
                yp = c * wd1;
            }
            #pragma unroll
            for (int mm = 32; mm >= 1; mm >>= 1) yp += __shfl_xor(yp, mm, 64);
            if (lane == 0) ya[wave] = yp;
        }

        // ---- B: acc = <h, Wr[:,tid]> (long; hides the y-reduction latency) ----
        float acc = 0.f;
        if (FAST) {
            const uint4* wc = ((const uint4*)Wsz) + tid;
            #pragma unroll 4
            for (int kc = 0; kc < 32; ++kc) {
                uint4 u = wc[kc * 1024];
                float4 ha = *(const float4*)&h_lds[kc * 8];
                float4 hb = *(const float4*)&h_lds[kc * 8 + 4];
                acc += ha.x * bf_lo(u.x) + ha.y * bf_hi(u.x)
                     + ha.z * bf_lo(u.y) + ha.w * bf_hi(u.y)
                     + hb.x * bf_lo(u.z) + hb.y * bf_hi(u.z)
                     + hb.z * bf_lo(u.w) + hb.w * bf_hi(u.w);
            }
        } else {
            #pragma unroll 8
            for (int p = 0; p < 256; ++p)
                acc += h_lds[p] * Wr[(size_t)p * 1024 + tid];
        }
        __syncthreads();                                   // alpha
        {
            float S = 0.f;
            #pragma unroll
            for (int w = 0; w < 16; ++w) S += sred[w];
            float ys = (ya[0] + ya[1] + ya[2] + ya[3]) * __builtin_amdgcn_rcpf(S)
                     + data_lds[t] * Wd0 + bd0;
            z_lds[tid] = acc + ys * wkc + blc;
        }
        __syncthreads();                                   // beta

        // ---- C: LSTM gates (i,f,g,o) ----
        if (tid < 256) {
            float zi = z_lds[tid];
            float zf = z_lds[256 + tid];
            float zg = z_lds[512 + tid];
            float zo = z_lds[768 + tid];
            float sn = sigmoid_acc(zf) * s_lds[tid] + sigmoid_acc(zi) * tanhf(zg);
            float hn = sigmoid_acc(zo) * tanhf(sn);
            s_lds[tid] = sn;
            h_lds[tid] = hn;
        }
        __syncthreads();                                   // gamma

        // ---- D: dscp[q][m] = <cat_quarter, Ww[q*128 .. ][m]> ----
        {
            const int m = tid & 255, q = tid >> 8;
            const float* cat = (q < 2) ? h_lds : s_lds;
            const int k0 = (q & 1) * 128;
            float a = 0.f;
            if (FAST) {
                const uint4* wwc = ((const uint4*)Wwsz) + m;
                #pragma unroll 4
                for (int i = 0; i < 16; ++i) {
                    uint4 u = wwc[(q * 16 + i) * 256];
                    float4 ca = *(const float4*)&cat[k0 + i * 8];
                    float4 cb = *(const float4*)&cat[k0 + i * 8 + 4];
                    a += ca.x * bf_lo(u.x) + ca.y * bf_hi(u.x)
                       + ca.z * bf_lo(u.y) + ca.w * bf_hi(u.y)
                       + cb.x * bf_lo(u.z) + cb.y * bf_hi(u.z)
                       + cb.z * bf_lo(u.w) + cb.w * bf_hi(u.w);
                }
            } else {
                const float* Wwh = Ww + (size_t)(q * 128) * 256 + m;
                #pragma unroll 4
                for (int k = 0; k < 128; k += 4) {
                    float4 c4 = *(const float4*)&cat[k0 + k];
                    a += c4.x * Wwh[(size_t)(k + 0) * 256]
                       + c4.y * Wwh[(size_t)(k + 1) * 256]
                       + c4.z * Wwh[(size_t)(k + 2) * 256]
                       + c4.w * Wwh[(size_t)(k + 3) * 256];
                }
            }
            dscp[q][m] = a;
        }
        __syncthreads();                                   // delta

        // ---- E: el[t'] = exp(<tanh(dsc + Ue[t']), Wv> + bv), Ue from registers ----
        {
            float dsc8[8];
            #pragma unroll
            for (int j = 0; j < 8; ++j)
                dsc8[j] = dscp[0][ml * 8 + j] + dscp[1][ml * 8 + j]
                        + dscp[2][ml * 8 + j] + dscp[3][ml * 8 + j] + bw8[j];

            float sum_ev = 0.f;
            #pragma unroll
            for (int q = 0; q < 8; ++q) {
                uint4 u = ue[q];
                float pl;
                pl  = fast_tanh(dsc8[0] + bf_lo(u.x)) * wv8[0];
                pl += fast_tanh(dsc8[1] + bf_hi(u.x)) * wv8[1];
                pl += fast_tanh(dsc8[2] + bf_lo(u.y)) * wv8[2];
                pl += fast_tanh(dsc8[3] + bf_hi(u.y)) * wv8[3];
                pl += fast_tanh(dsc8[4] + bf_lo(u.z)) * wv8[4];
                pl += fast_tanh(dsc8[5] + bf_hi(u.z)) * wv8[5];
                pl += fast_tanh(dsc8[6] + bf_lo(u.w)) * wv8[6];
                pl += fast_tanh(dsc8[7] + bf_hi(u.w)) * wv8[7];
                #pragma unroll
                for (int mm = 16; mm >= 1; mm >>= 1) pl += __shfl_xor(pl, mm, 64);
                if (ml == 0) {
                    float ev = exp2f((pl + bv0) * 1.44269504f);
                    el_lds[wave * 16 + 2 * q + hl] = ev;
                    sum_ev += ev;
                }
            }
            sum_ev += __shfl_xor(sum_ev, 32, 64);
            if (lane == 0) sred[wave] = sum_ev;
        }
        __syncthreads();                                   // eps

        // ---- F: raw ctx partials from bf16 enc ----
        {
            float a0 = 0.f, a1 = 0.f, a2 = 0.f, a3 = 0.f;
            #pragma unroll 4
            for (int i = 0; i < 16; ++i) {
                const int tp = wave * 16 + i;
                float w = el_lds[tp];
                uint2 u = encB[tp * 64 + lane];
                a0 += w * bf_lo(u.x); a1 += w * bf_hi(u.x);
                a2 += w * bf_lo(u.y); a3 += w * bf_hi(u.y);
            }
            *(float4*)&ctxp[wave][lane * 4] = make_float4(a0, a1, a2, a3);
        }
        __syncthreads();                                   // zeta
    }

    // ---- epilogue ----
    {
        float qp = 0.f;
        if (tid < 256) {
            float S = 0.f, c = 0.f;
            #pragma unroll
            for (int w = 0; w < 16; ++w) { S += sred[w]; c += ctxp[w][tid]; }
            float ctx = c * __builtin_amdgcn_rcpf(S);
            qp = h_lds[tid] * Wvb[tid] + ctx * Wvb[256 + tid];
        }
        if (wave < 4) {
            #pragma unroll
            for (int mm = 32; mm >= 1; mm >>= 1) qp += __shfl_xor(qp, mm, 64);
            if (lane == 0) ya[wave] = qp;
        }
        __syncthreads();
        if (tid < 256) {
            float qv = ya[0] + ya[1] + ya[2] + ya[3] + bvb[0];
            out[b * 256 + tid] = qv * Wwb[tid] + bwb[tid];
        }
    }
}

extern "C" void kernel_launch(void* const* d_in, const int* in_sizes, int n_in,
                              void* d_out, int out_size, void* d_ws, size_t ws_size,
                              hipStream_t stream) {
    const float* data = (const float*)d_in[0];
    const float* enc  = (const float*)d_in[1];
    const float* h0   = (const float*)d_in[2];
    const float* s0   = (const float*)d_in[3];
    const float* Wd   = (const float*)d_in[4];
    const float* bd   = (const float*)d_in[5];
    const float* Wk   = (const float*)d_in[6];
    const float* Wr   = (const float*)d_in[7];
    const float* bl   = (const float*)d_in[8];
    const float* Ww   = (const float*)d_in[9];
    const float* bw   = (const float*)d_in[10];
    const float* Wu   = (const float*)d_in[11];
    const float* bu   = (const float*)d_in[12];
    const float* Wv   = (const float*)d_in[13];
    const float* bv   = (const float*)d_in[14];
    const float* Wvb  = (const float*)d_in[15];
    const float* bvb  = (const float*)d_in[16];
    const float* Wwb  = (const float*)d_in[17];
    const float* bwb  = (const float*)d_in[18];

    ushort* Ue16  = (ushort*)d_ws;                                   // 32 MB
    ushort* enc16 = (ushort*)((char*)d_ws + (32ull << 20));          // 32 MB
    ushort* Wsz   = (ushort*)((char*)d_ws + (64ull << 20));          // 512 KB
    ushort* Wwsz  = (ushort*)((char*)d_ws + (64ull << 20) + (512ull << 10)); // 256 KB
    const bool fast = ws_size >= (64ull << 20) + (768ull << 10);
    float* out = (float*)d_out;

    hipLaunchKernelGGL(ue_gemm, dim3((B * T) / 32), dim3(256), 0, stream,
                       enc, Wu, bu, Ue16);
    hipLaunchKernelGGL(enc_cvt, dim3((B * T * M / 4) / 256), dim3(256), 0, stream,
                       (const float4*)enc, (uint2*)enc16);
    if (fast) {
        hipLaunchKernelGGL(wr_cvt, dim3(128), dim3(256), 0, stream, Wr, Wsz);
        hipLaunchKernelGGL(ww_cvt, dim3(64), dim3(256), 0, stream, Ww, Wwsz);
        hipLaunchKernelGGL(decoder_scan<1>, dim3(B), dim3(NT), 0, stream,
                           data, h0, s0, Wd, bd, Wk, Wr, bl, Ww, bw,
                           Wv, bv, Wvb, bvb, Wwb, bwb, Ue16, enc16, Wsz, Wwsz, out);
    } else {
        hipLaunchKernelGGL(decoder_scan<0>, dim3(B), dim3(NT), 0, stream,
                           data, h0, s0, Wd, bd, Wk, Wr, bl, Ww, bw,
                           Wv, bv, Wvb, bvb, Wwb, bwb, Ue16, enc16, Wsz, Wwsz, out);
    }
}

// Round 4
// 7560.045 us; speedup vs baseline: 1.6495x; 1.1428x over previous
//
#include <hip/hip_runtime.h>
#include <hip/hip_bf16.h>

#define B 256
#define T 256
#define M 256
#define P 256
#define TSTEPS 255
#define NT 1024

typedef unsigned int uint;
typedef unsigned short ushort;
typedef _Float16 hf2 __attribute__((ext_vector_type(2)));

__device__ __forceinline__ float fast_tanh(float x) {
    float e = exp2f(x * 2.885390082f);             // e^(2x)
    return 1.f - 2.f * __builtin_amdgcn_rcpf(e + 1.f);
}
__device__ __forceinline__ float fast_sigmoid(float x) {
    float e = exp2f(-x * 1.442695041f);            // e^(-x)
    return __builtin_amdgcn_rcpf(1.f + e);
}

#if defined(__has_builtin)
#if __has_builtin(__builtin_amdgcn_fdot2)
#define HAVE_FDOT2 1
#endif
#endif

__device__ __forceinline__ float dot2(uint a, uint b, float c) {
#ifdef HAVE_FDOT2
    return __builtin_amdgcn_fdot2(__builtin_bit_cast(hf2, a),
                                  __builtin_bit_cast(hf2, b), c, false);
#else
    hf2 x = __builtin_bit_cast(hf2, a), y = __builtin_bit_cast(hf2, b);
    return c + (float)x.x * (float)y.x + (float)x.y * (float)y.y;
#endif
}

__device__ __forceinline__ uint pk16(float a, float b) {
    return __builtin_bit_cast(uint, __builtin_amdgcn_cvt_pkrtz(a, b));
}

// ---------------- Ue16 = f16(encoder_h @ Wu + bu) ----------------
__global__ __launch_bounds__(256) void ue_gemm(
    const float* __restrict__ enc, const float* __restrict__ Wu,
    const float* __restrict__ bu, _Float16* __restrict__ Ue16)
{
    __shared__ float At[32][256];
    const int r0 = blockIdx.x * 32;
    const int tid = threadIdx.x;

    #pragma unroll 4
    for (int i = 0; i < 32; ++i)
        At[i][tid] = enc[(size_t)(r0 + i) * 256 + tid];
    __syncthreads();

    float acc[32];
    #pragma unroll
    for (int r = 0; r < 32; ++r) acc[r] = 0.f;

    for (int k = 0; k < 256; k += 4) {
        float w0 = Wu[(size_t)(k + 0) * 256 + tid];
        float w1 = Wu[(size_t)(k + 1) * 256 + tid];
        float w2 = Wu[(size_t)(k + 2) * 256 + tid];
        float w3 = Wu[(size_t)(k + 3) * 256 + tid];
        #pragma unroll
        for (int r = 0; r < 32; ++r) {
            float4 a4 = *(const float4*)&At[r][k];
            acc[r] += a4.x * w0 + a4.y * w1 + a4.z * w2 + a4.w * w3;
        }
    }
    float bub = bu[tid];
    #pragma unroll 4
    for (int r = 0; r < 32; ++r)
        Ue16[(size_t)(r0 + r) * 256 + tid] = (_Float16)(acc[r] + bub);
}

// ---- Wsz[kc*1024+c] = uint4 of f16 pairs of Wr[kc*8+j][c], j=0..7 ----
__global__ __launch_bounds__(256) void wr_cvt(
    const float* __restrict__ Wr, uint4* __restrict__ Wsz)
{
    int i = blockIdx.x * 256 + threadIdx.x;        // 32768
    int kc = i >> 10, c = i & 1023;
    const float* s = Wr + (size_t)kc * 8 * 1024 + c;
    uint4 o;
    o.x = pk16(s[0 * 1024], s[1 * 1024]);
    o.y = pk16(s[2 * 1024], s[3 * 1024]);
    o.z = pk16(s[4 * 1024], s[5 * 1024]);
    o.w = pk16(s[6 * 1024], s[7 * 1024]);
    Wsz[i] = o;
}

// ---- Wwsz[kk*256+m] = uint4 of f16 pairs of Ww[kk*8+j][m], j=0..7 ----
__global__ __launch_bounds__(256) void ww_cvt(
    const float* __restrict__ Ww, uint4* __restrict__ Wwsz)
{
    int i = blockIdx.x * 256 + threadIdx.x;        // 16384
    int kk = i >> 8, m = i & 255;
    const float* s = Ww + (size_t)kk * 8 * 256 + m;
    uint4 o;
    o.x = pk16(s[0 * 256], s[1 * 256]);
    o.y = pk16(s[2 * 256], s[3 * 256]);
    o.z = pk16(s[4 * 256], s[5 * 256]);
    o.w = pk16(s[6 * 256], s[7 * 256]);
    Wwsz[i] = o;
}

// ---------------- main scan: one block (1024 thr) per batch element ----------------
__global__ __launch_bounds__(NT, 4) void decoder_scan(
    const float* __restrict__ data,
    const float* __restrict__ h0,  const float* __restrict__ s0,
    const float* __restrict__ Wd,  const float* __restrict__ bd,
    const float* __restrict__ Wk,  const float* __restrict__ bl,
    const float* __restrict__ bw,
    const float* __restrict__ Wv,  const float* __restrict__ bv,
    const float* __restrict__ Wvb, const float* __restrict__ bvb,
    const float* __restrict__ Wwb, const float* __restrict__ bwb,
    const float* __restrict__ enc,
    const _Float16* __restrict__ Ue16g,
    const uint4* __restrict__ Wsz, const uint4* __restrict__ Wwsz,
    float* __restrict__ out)
{
    const int b    = blockIdx.x;
    const int tid  = threadIdx.x;
    const int lane = tid & 63;
    const int wave = tid >> 6;          // 0..15
    const int ml   = lane & 31;
    const int hl   = lane >> 5;

    __shared__ float h_lds[P], s_lds[P];
    __shared__ uint  h2_lds[P / 2], s2_lds[P / 2];
    __shared__ float z_lds[4 * P];
    __shared__ __align__(16) float dscp[4][M];
    __shared__ float el_lds[T];
    __shared__ float g_lds[T];
    __shared__ float ctx_lds[M];
    __shared__ __align__(16) float sred[16];
    __shared__ __align__(16) float yred[16];
    __shared__ float ya[4];
    __shared__ float data_lds[TSTEPS + 1];

    // ---- init state ----
    if (tid < 256) {
        float hv = h0[b * 256 + tid], sv = s0[b * 256 + tid];
        h_lds[tid] = hv; s_lds[tid] = sv; ctx_lds[tid] = 0.f;
        float hv1 = __shfl_down(hv, 1, 64);
        float sv1 = __shfl_down(sv, 1, 64);
        if (!(tid & 1)) {
            h2_lds[tid >> 1] = pk16(hv, hv1);
            s2_lds[tid >> 1] = pk16(sv, sv1);
        }
    }
    if (tid < 16) { sred[tid] = 1.f; yred[tid] = 0.f; }
    if (tid < TSTEPS) data_lds[tid] = data[b * TSTEPS + tid];

    // ---- Ue slice into registers: row = wave*16 + 2q + hl, 8 f16 at ml*8 ----
    uint4 ue[8];
    {
        const uint4* ueb = (const uint4*)(Ue16g + (size_t)b * T * M);
        #pragma unroll
        for (int q = 0; q < 8; ++q)
            ue[q] = ueb[(wave * 16 + 2 * q + hl) * 32 + ml];
    }

    // ---- constants ----
    const float Wd0 = Wd[0], bd0 = bd[0], bv0 = bv[0];
    const float wkc = Wk[tid], blc = bl[tid];
    float wv8[8], bw8[8];
    #pragma unroll
    for (int j = 0; j < 8; ++j) { wv8[j] = Wv[ml * 8 + j]; bw8[j] = bw[ml * 8 + j]; }

    const float* encB = enc + (size_t)b * T * M;

    // ---- g[tp] = <enc[tp,:], Wd[1:]>  (step-invariant y projection) ----
    {
        float w0 = Wd[1 + lane * 4], w1 = Wd[2 + lane * 4];
        float w2 = Wd[3 + lane * 4], w3 = Wd[4 + lane * 4];
        for (int i = 0; i < 16; ++i) {
            int tp = wave * 16 + i;
            float4 e4 = *(const float4*)&encB[(size_t)tp * 256 + lane * 4];
            float p = e4.x * w0 + e4.y * w1 + e4.z * w2 + e4.w * w3;
            #pragma unroll
            for (int mm = 32; mm >= 1; mm >>= 1) p += __shfl_xor(p, mm, 64);
            if (lane == 0) g_lds[tp] = p;
        }
    }
    __syncthreads();

    const uint4* wc   = Wsz + tid;
    const uint4* h2u4 = (const uint4*)h2_lds;

    for (int t = 0; t < TSTEPS; ++t) {
        // ---- z-combine scalars (from prev step's E) ----
        float S, Y;
        {
            float4 sa = *(const float4*)&sred[0],  sb = *(const float4*)&sred[4];
            float4 sc = *(const float4*)&sred[8],  sd = *(const float4*)&sred[12];
            float4 yaa = *(const float4*)&yred[0], yab = *(const float4*)&yred[4];
            float4 yac = *(const float4*)&yred[8], yad = *(const float4*)&yred[12];
            S = (sa.x+sa.y+sa.z+sa.w) + (sb.x+sb.y+sb.z+sb.w)
              + (sc.x+sc.y+sc.z+sc.w) + (sd.x+sd.y+sd.z+sd.w);
            Y = (yaa.x+yaa.y+yaa.z+yaa.w) + (yab.x+yab.y+yab.z+yab.w)
              + (yac.x+yac.y+yac.z+yac.w) + (yad.x+yad.y+yad.z+yad.w);
        }
        const float ys = Y * __builtin_amdgcn_rcpf(S) + data_lds[t] * Wd0 + bd0;

        // ---- B: acc = <h, Wr[:,tid]> via f16 dot2 ----
        float acc = 0.f;
        #pragma unroll 4
        for (int kc = 0; kc < 32; ++kc) {
            uint4 w = wc[kc << 10];
            uint4 h = h2u4[kc];
            acc = dot2(w.x, h.x, acc);
            acc = dot2(w.y, h.y, acc);
            acc = dot2(w.z, h.z, acc);
            acc = dot2(w.w, h.w, acc);
        }
        z_lds[tid] = acc + ys * wkc + blc;
        __syncthreads();                                   // beta

        // ---- C: LSTM gates ----
        if (tid < 256) {
            float zi = z_lds[tid];
            float zf = z_lds[256 + tid];
            float zg = z_lds[512 + tid];
            float zo = z_lds[768 + tid];
            float sn = fast_sigmoid(zf) * s_lds[tid] + fast_sigmoid(zi) * fast_tanh(zg);
            float hn = fast_sigmoid(zo) * fast_tanh(sn);
            s_lds[tid] = sn; h_lds[tid] = hn;
            float hn1 = __shfl_down(hn, 1, 64);
            float sn1 = __shfl_down(sn, 1, 64);
            if (!(tid & 1)) {
                h2_lds[tid >> 1] = pk16(hn, hn1);
                s2_lds[tid >> 1] = pk16(sn, sn1);
            }
        }
        __syncthreads();                                   // gamma

        // ---- D: dscp[q][m] = <cat_quarter, Ww_quarter[:,m]> via dot2 ----
        {
            const int m = tid & 255, q = tid >> 8;
            const uint4* cat4 = (const uint4*)((q < 2) ? h2_lds : s2_lds) + ((q & 1) << 4);
            const uint4* ww = Wwsz + ((size_t)(q << 4) << 8) + m;
            float a = 0.f;
            #pragma unroll 4
            for (int i = 0; i < 16; ++i) {
                uint4 w = ww[i << 8];
                uint4 c = cat4[i];
                a = dot2(w.x, c.x, a);
                a = dot2(w.y, c.y, a);
                a = dot2(w.z, c.z, a);
                a = dot2(w.w, c.w, a);
            }
            dscp[q][m] = a;
        }
        __syncthreads();                                   // delta

        // ---- E: logits, exp, and the Σev / Σev·g reductions ----
        {
            float dsc8[8];
            #pragma unroll
            for (int j = 0; j < 2; ++j) {
                float4 d0 = *(const float4*)&dscp[0][ml * 8 + j * 4];
                float4 d1 = *(const float4*)&dscp[1][ml * 8 + j * 4];
                float4 d2 = *(const float4*)&dscp[2][ml * 8 + j * 4];
                float4 d3 = *(const float4*)&dscp[3][ml * 8 + j * 4];
                dsc8[j*4+0] = d0.x + d1.x + d2.x + d3.x + bw8[j*4+0];
                dsc8[j*4+1] = d0.y + d1.y + d2.y + d3.y + bw8[j*4+1];
                dsc8[j*4+2] = d0.z + d1.z + d2.z + d3.z + bw8[j*4+2];
                dsc8[j*4+3] = d0.w + d1.w + d2.w + d3.w + bw8[j*4+3];
            }
            float sum_ev = 0.f, sum_yg = 0.f;
            #pragma unroll
            for (int q = 0; q < 8; ++q) {
                uint4 u = ue[q];
                hf2 p0 = __builtin_bit_cast(hf2, u.x);
                hf2 p1 = __builtin_bit_cast(hf2, u.y);
                hf2 p2 = __builtin_bit_cast(hf2, u.z);
                hf2 p3 = __builtin_bit_cast(hf2, u.w);
                float pl;
                pl  = fast_tanh(dsc8[0] + (float)p0.x) * wv8[0];
                pl += fast_tanh(dsc8[1] + (float)p0.y) * wv8[1];
                pl += fast_tanh(dsc8[2] + (float)p1.x) * wv8[2];
                pl += fast_tanh(dsc8[3] + (float)p1.y) * wv8[3];
                pl += fast_tanh(dsc8[4] + (float)p2.x) * wv8[4];
                pl += fast_tanh(dsc8[5] + (float)p2.y) * wv8[5];
                pl += fast_tanh(dsc8[6] + (float)p3.x) * wv8[6];
                pl += fast_tanh(dsc8[7] + (float)p3.y) * wv8[7];
                #pragma unroll
                for (int mm = 16; mm >= 1; mm >>= 1) pl += __shfl_xor(pl, mm, 64);
                if (ml == 0) {
                    int tp = wave * 16 + 2 * q + hl;
                    float ev = exp2f((pl + bv0) * 1.442695041f);
                    el_lds[tp] = ev;
                    sum_ev += ev;
                    sum_yg += ev * g_lds[tp];
                }
            }
            sum_ev += __shfl_xor(sum_ev, 32, 64);
            sum_yg += __shfl_xor(sum_yg, 32, 64);
            if (lane == 0) { sred[wave] = sum_ev; yred[wave] = sum_yg; }
        }
        __syncthreads();                                   // zeta
    }

    // ---- epilogue: final ctx from el(254) + fp32 enc, then output head ----
    {
        float S = 0.f;
        {
            float4 sa = *(const float4*)&sred[0],  sb = *(const float4*)&sred[4];
            float4 sc = *(const float4*)&sred[8],  sd = *(const float4*)&sred[12];
            S = (sa.x+sa.y+sa.z+sa.w) + (sb.x+sb.y+sb.z+sb.w)
              + (sc.x+sc.y+sc.z+sc.w) + (sd.x+sd.y+sd.z+sd.w);
        }
        float a0 = 0.f, a1 = 0.f, a2 = 0.f, a3 = 0.f;
        for (int i = 0; i < 16; ++i) {
            int tp = wave * 16 + i;
            float w = el_lds[tp];
            float4 e4 = *(const float4*)&encB[(size_t)tp * 256 + lane * 4];
            a0 += w * e4.x; a1 += w * e4.y; a2 += w * e4.z; a3 += w * e4.w;
        }
        atomicAdd(&ctx_lds[lane * 4 + 0], a0);
        atomicAdd(&ctx_lds[lane * 4 + 1], a1);
        atomicAdd(&ctx_lds[lane * 4 + 2], a2);
        atomicAdd(&ctx_lds[lane * 4 + 3], a3);
        __syncthreads();

        float qp = 0.f;
        if (tid < 256) {
            float ctx = ctx_lds[tid] * __builtin_amdgcn_rcpf(S);
            qp = h_lds[tid] * Wvb[tid] + ctx * Wvb[256 + tid];
        }
        if (wave < 4) {
            #pragma unroll
            for (int mm = 32; mm >= 1; mm >>= 1) qp += __shfl_xor(qp, mm, 64);
            if (lane == 0) ya[wave] = qp;
        }
        __syncthreads();
        if (tid < 256) {
            float qv = ya[0] + ya[1] + ya[2] + ya[3] + bvb[0];
            out[b * 256 + tid] = qv * Wwb[tid] + bwb[tid];
        }
    }
}

extern "C" void kernel_launch(void* const* d_in, const int* in_sizes, int n_in,
                              void* d_out, int out_size, void* d_ws, size_t ws_size,
                              hipStream_t stream) {
    const float* data = (const float*)d_in[0];
    const float* enc  = (const float*)d_in[1];
    const float* h0   = (const float*)d_in[2];
    const float* s0   = (const float*)d_in[3];
    const float* Wd   = (const float*)d_in[4];
    const float* bd   = (const float*)d_in[5];
    const float* Wk   = (const float*)d_in[6];
    const float* Wr   = (const float*)d_in[7];
    const float* bl   = (const float*)d_in[8];
    const float* Ww   = (const float*)d_in[9];
    const float* bw   = (const float*)d_in[10];
    const float* Wu   = (const float*)d_in[11];
    const float* bu   = (const float*)d_in[12];
    const float* Wv   = (const float*)d_in[13];
    const float* bv   = (const float*)d_in[14];
    const float* Wvb  = (const float*)d_in[15];
    const float* bvb  = (const float*)d_in[16];
    const float* Wwb  = (const float*)d_in[17];
    const float* bwb  = (const float*)d_in[18];

    _Float16* Ue16 = (_Float16*)d_ws;                                 // 32 MB
    uint4* Wsz  = (uint4*)((char*)d_ws + (32ull << 20));              // 512 KB
    uint4* Wwsz = (uint4*)((char*)d_ws + (32ull << 20) + (512ull << 10)); // 256 KB
    float* out = (float*)d_out;

    hipLaunchKernelGGL(ue_gemm, dim3((B * T) / 32), dim3(256), 0, stream,
                       enc, Wu, bu, Ue16);
    hipLaunchKernelGGL(wr_cvt, dim3(128), dim3(256), 0, stream, Wr, Wsz);
    hipLaunchKernelGGL(ww_cvt, dim3(64), dim3(256), 0, stream, Ww, Wwsz);
    hipLaunchKernelGGL(decoder_scan, dim3(B), dim3(NT), 0, stream,
                       data, h0, s0, Wd, bd, Wk, bl, bw,
                       Wv, bv, Wvb, bvb, Wwb, bwb,
                       enc, Ue16, Wsz, Wwsz, out);
}

// Round 5
// 4020.266 us; speedup vs baseline: 3.1018x; 1.8805x over previous
//
#include <hip/hip_runtime.h>
#include <hip/hip_bf16.h>

#define B 256
#define T 256
#define M 256
#define P 256
#define TSTEPS 255
#define NT 1024

typedef unsigned int uint;
typedef _Float16 hf2 __attribute__((ext_vector_type(2)));

__device__ __forceinline__ float fast_tanh(float x) {
    float e = exp2f(x * 2.885390082f);             // e^(2x)
    return 1.f - 2.f * __builtin_amdgcn_rcpf(e + 1.f);
}
__device__ __forceinline__ float fast_sigmoid(float x) {
    float e = exp2f(-x * 1.442695041f);            // e^(-x)
    return __builtin_amdgcn_rcpf(1.f + e);
}

#if defined(__has_builtin)
#if __has_builtin(__builtin_amdgcn_fdot2)
#define HAVE_FDOT2 1
#endif
#endif

__device__ __forceinline__ float dot2(uint a, uint b, float c) {
#ifdef HAVE_FDOT2
    return __builtin_amdgcn_fdot2(__builtin_bit_cast(hf2, a),
                                  __builtin_bit_cast(hf2, b), c, false);
#else
    hf2 x = __builtin_bit_cast(hf2, a), y = __builtin_bit_cast(hf2, b);
    return c + (float)x.x * (float)y.x + (float)x.y * (float)y.y;
#endif
}

__device__ __forceinline__ uint pk16(float a, float b) {
    return __builtin_bit_cast(uint, __builtin_amdgcn_cvt_pkrtz(a, b));
}

// ---------------- Ue16 = f16(encoder_h @ Wu + bu) ----------------
__global__ __launch_bounds__(256) void ue_gemm(
    const float* __restrict__ enc, const float* __restrict__ Wu,
    const float* __restrict__ bu, _Float16* __restrict__ Ue16)
{
    __shared__ float At[32][256];
    const int r0 = blockIdx.x * 32;
    const int tid = threadIdx.x;

    #pragma unroll 4
    for (int i = 0; i < 32; ++i)
        At[i][tid] = enc[(size_t)(r0 + i) * 256 + tid];
    __syncthreads();

    float acc[32];
    #pragma unroll
    for (int r = 0; r < 32; ++r) acc[r] = 0.f;

    for (int k = 0; k < 256; k += 4) {
        float w0 = Wu[(size_t)(k + 0) * 256 + tid];
        float w1 = Wu[(size_t)(k + 1) * 256 + tid];
        float w2 = Wu[(size_t)(k + 2) * 256 + tid];
        float w3 = Wu[(size_t)(k + 3) * 256 + tid];
        #pragma unroll
        for (int r = 0; r < 32; ++r) {
            float4 a4 = *(const float4*)&At[r][k];
            acc[r] += a4.x * w0 + a4.y * w1 + a4.z * w2 + a4.w * w3;
        }
    }
    float bub = bu[tid];
    #pragma unroll 4
    for (int r = 0; r < 32; ++r)
        Ue16[(size_t)(r0 + r) * 256 + tid] = (_Float16)(acc[r] + bub);
}

// ---- Wsz[kc*1024+c] = uint4 of f16 pairs of Wr[kc*8+j][c], j=0..7 ----
__global__ __launch_bounds__(256) void wr_cvt(
    const float* __restrict__ Wr, uint4* __restrict__ Wsz)
{
    int i = blockIdx.x * 256 + threadIdx.x;        // 32768
    int kc = i >> 10, c = i & 1023;
    const float* s = Wr + (size_t)kc * 8 * 1024 + c;
    uint4 o;
    o.x = pk16(s[0 * 1024], s[1 * 1024]);
    o.y = pk16(s[2 * 1024], s[3 * 1024]);
    o.z = pk16(s[4 * 1024], s[5 * 1024]);
    o.w = pk16(s[6 * 1024], s[7 * 1024]);
    Wsz[i] = o;
}

// ---- Wwsz[kk*256+m] = uint4 of f16 pairs of Ww[kk*8+j][m], j=0..7 ----
__global__ __launch_bounds__(256) void ww_cvt(
    const float* __restrict__ Ww, uint4* __restrict__ Wwsz)
{
    int i = blockIdx.x * 256 + threadIdx.x;        // 16384
    int kk = i >> 8, m = i & 255;
    const float* s = Ww + (size_t)kk * 8 * 256 + m;
    uint4 o;
    o.x = pk16(s[0 * 256], s[1 * 256]);
    o.y = pk16(s[2 * 256], s[3 * 256]);
    o.z = pk16(s[4 * 256], s[5 * 256]);
    o.w = pk16(s[6 * 256], s[7 * 256]);
    Wwsz[i] = o;
}

// ---------------- main scan: one block (1024 thr) per batch element ----------------
// Wave-specialized pipeline: waves 0-7 stream Wr (acc for t+1), waves 8-15 run
// attention (D_t, E_t); both consume h_{t+1} produced by the quad-gate phase P1.
__global__ __launch_bounds__(NT, 4) void decoder_scan(
    const float* __restrict__ data,
    const float* __restrict__ h0,  const float* __restrict__ s0,
    const float* __restrict__ Wd,  const float* __restrict__ bd,
    const float* __restrict__ Wk,  const float* __restrict__ bl,
    const float* __restrict__ bw,
    const float* __restrict__ Wv,  const float* __restrict__ bv,
    const float* __restrict__ Wvb, const float* __restrict__ bvb,
    const float* __restrict__ Wwb, const float* __restrict__ bwb,
    const float* __restrict__ enc,
    const _Float16* __restrict__ Ue16g,
    const uint4* __restrict__ Wsz, const uint4* __restrict__ Wwsz,
    float* __restrict__ out)
{
    const int b    = blockIdx.x;
    const int tid  = threadIdx.x;
    const int lane = tid & 63;
    const int wave = tid >> 6;          // 0..15
    const int ml   = lane & 31;
    const int hl   = lane >> 5;

    __shared__ _Float16 ue_lds[T * M];  // 128 KB
    __shared__ float h_lds[P], s_lds[P];
    __shared__ uint  h2_lds[P / 2], s2_lds[P / 2];
    __shared__ float z_lds[4 * P];      // raw acc (matvec only)
    __shared__ __align__(16) float dscp[4][M];
    __shared__ float el_lds[T];
    __shared__ float g_lds[T];
    __shared__ float ctx_lds[M];
    __shared__ __align__(16) float sred[8], yred[8];
    __shared__ float ya[4];
    __shared__ float data_lds[TSTEPS + 1];

    // ---- stage Ue into LDS (8192 uint4 = 128 KB) ----
    {
        const uint4* src = (const uint4*)(Ue16g + (size_t)b * T * M);
        uint4* dst = (uint4*)ue_lds;
        #pragma unroll
        for (int i = 0; i < 8; ++i) dst[tid + i * NT] = src[tid + i * NT];
    }
    if (tid < 256) {
        float hv = h0[b * 256 + tid], sv = s0[b * 256 + tid];
        h_lds[tid] = hv; s_lds[tid] = sv; ctx_lds[tid] = 0.f;
        float hv1 = __shfl_down(hv, 1, 64);
        float sv1 = __shfl_down(sv, 1, 64);
        if (!(tid & 1)) {
            h2_lds[tid >> 1] = pk16(hv, hv1);
            s2_lds[tid >> 1] = pk16(sv, sv1);
        }
    }
    if (tid < 8) { sred[tid] = 1.f; yred[tid] = 0.f; }   // ctx_0 = 0
    if (tid < TSTEPS) data_lds[tid] = data[b * TSTEPS + tid];

    // ---- constants ----
    const float Wd0 = Wd[0], bd0 = bd[0], bv0 = bv[0];
    const int   gate = tid & 3, uu = tid >> 2;
    const int   cp = gate * 256 + uu;               // this thread's z column (P1)
    const float wkp = Wk[cp], blp = bl[cp];

    const float* encB = enc + (size_t)b * T * M;

    // ---- g[tp] = <enc[tp,:], Wd[1:]>  (step-invariant y projection) ----
    {
        float w0 = Wd[1 + lane * 4], w1 = Wd[2 + lane * 4];
        float w2 = Wd[3 + lane * 4], w3 = Wd[4 + lane * 4];
        for (int i = 0; i < 16; ++i) {
            int tp = wave * 16 + i;
            float4 e4 = *(const float4*)&encB[(size_t)tp * 256 + lane * 4];
            float p = e4.x * w0 + e4.y * w1 + e4.z * w2 + e4.w * w3;
            #pragma unroll
            for (int mm = 32; mm >= 1; mm >>= 1) p += __shfl_xor(p, mm, 64);
            if (lane == 0) g_lds[tp] = p;
        }
    }
    __syncthreads();

    const uint4* h2u4 = (const uint4*)h2_lds;
    const uint4* s2u4 = (const uint4*)s2_lds;

    // ---- prologue: acc_0 = Wr·h_0 into z_lds (1 col per thread, all waves) ----
    {
        const uint4* wc = Wsz + tid;
        float acc = 0.f;
        #pragma unroll 4
        for (int kc = 0; kc < 32; ++kc) {
            uint4 w = wc[kc << 10];
            uint4 h = h2u4[kc];
            acc = dot2(w.x, h.x, acc); acc = dot2(w.y, h.y, acc);
            acc = dot2(w.z, h.z, acc); acc = dot2(w.w, h.w, acc);
        }
        z_lds[tid] = acc;
    }
    __syncthreads();

    // ---- per-group constants ----
    const int aw  = wave - 8;                        // A-wave index 0..7
    const int aid = tid - 512;                       // A-thread id 0..511
    const int dq  = (aid >> 7) & 3, dm = aid & 127;  // D: quarter, m-col
    float wv8[8], bw8[8];
    #pragma unroll
    for (int j = 0; j < 8; ++j) { wv8[j] = Wv[ml * 8 + j]; bw8[j] = bw[ml * 8 + j]; }
    const uint4* wcA = Wsz + tid;                    // G: col tid
    const uint4* wcB = Wsz + tid + 512;              // G: col tid+512

    float accA = 0.f, accB = 0.f;

    for (int t = 0; t < TSTEPS; ++t) {
        // ---- P1: ys; z = acc_raw + ys*wk + bl; quad-shfl LSTM gates ----
        {
            float4 sa = *(const float4*)&sred[0], sb = *(const float4*)&sred[4];
            float4 yaa = *(const float4*)&yred[0], yab = *(const float4*)&yred[4];
            float S = sa.x + sa.y + sa.z + sa.w + sb.x + sb.y + sb.z + sb.w;
            float Y = yaa.x + yaa.y + yaa.z + yaa.w + yab.x + yab.y + yab.z + yab.w;
            float ys = Y * __builtin_amdgcn_rcpf(S) + data_lds[t] * Wd0 + bd0;
            float zc = z_lds[cp] + ys * wkp + blp;
            float nl = (gate == 2) ? fast_tanh(zc) : fast_sigmoid(zc);
            float n1 = __shfl_xor(nl, 1, 64);
            float n2 = __shfl_xor(nl, 2, 64);
            float n3 = __shfl_xor(nl, 3, 64);
            float hn = 0.f, snv = 0.f;
            if (gate == 0) {                          // nl=sig_i n1=sig_f n2=tanh_g n3=sig_o
                float s_old = s_lds[uu];
                snv = n1 * s_old + nl * n2;
                hn  = n3 * fast_tanh(snv);
                s_lds[uu] = snv; h_lds[uu] = hn;
            }
            float hn4 = __shfl_down(hn, 4, 64);
            float sn4 = __shfl_down(snv, 4, 64);
            if ((tid & 7) == 0) {
                h2_lds[uu >> 1] = pk16(hn, hn4);
                s2_lds[uu >> 1] = pk16(snv, sn4);
            }
        }
        __syncthreads();                               // X: h_{t+1} ready

        // ---- P2: G: acc kc 0..15   |   A: D_t (dscp) ----
        if (wave < 8) {
            accA = 0.f; accB = 0.f;
            #pragma unroll 4
            for (int kc = 0; kc < 16; ++kc) {
                uint4 wA = wcA[kc << 10], wB = wcB[kc << 10];
                uint4 h = h2u4[kc];
                accA = dot2(wA.x, h.x, accA); accA = dot2(wA.y, h.y, accA);
                accA = dot2(wA.z, h.z, accA); accA = dot2(wA.w, h.w, accA);
                accB = dot2(wB.x, h.x, accB); accB = dot2(wB.y, h.y, accB);
                accB = dot2(wB.z, h.z, accB); accB = dot2(wB.w, h.w, accB);
            }
        } else {
            const uint4* cat4 = ((dq < 2) ? h2u4 : s2u4) + ((dq & 1) << 4);
            const uint4* wwp  = Wwsz + (dq << 12) + dm;
            float a0 = 0.f, a1 = 0.f;
            #pragma unroll 4
            for (int i = 0; i < 16; ++i) {
                uint4 c  = cat4[i];
                uint4 w0 = wwp[i << 8];
                uint4 w1 = wwp[(i << 8) + 128];
                a0 = dot2(w0.x, c.x, a0); a0 = dot2(w0.y, c.y, a0);
                a0 = dot2(w0.z, c.z, a0); a0 = dot2(w0.w, c.w, a0);
                a1 = dot2(w1.x, c.x, a1); a1 = dot2(w1.y, c.y, a1);
                a1 = dot2(w1.z, c.z, a1); a1 = dot2(w1.w, c.w, a1);
            }
            dscp[dq][dm] = a0; dscp[dq][dm + 128] = a1;
        }
        __syncthreads();                               // Y: dscp ready

        // ---- P3: G: acc kc 16..31 + write z   |   A: E_t ----
        if (wave < 8) {
            #pragma unroll 4
            for (int kc = 16; kc < 32; ++kc) {
                uint4 wA = wcA[kc << 10], wB = wcB[kc << 10];
                uint4 h = h2u4[kc];
                accA = dot2(wA.x, h.x, accA); accA = dot2(wA.y, h.y, accA);
                accA = dot2(wA.z, h.z, accA); accA = dot2(wA.w, h.w, accA);
                accB = dot2(wB.x, h.x, accB); accB = dot2(wB.y, h.y, accB);
                accB = dot2(wB.z, h.z, accB); accB = dot2(wB.w, h.w, accB);
            }
            z_lds[tid] = accA; z_lds[tid + 512] = accB;
        } else {
            float dsc8[8];
            #pragma unroll
            for (int jb = 0; jb < 2; ++jb) {
                float4 d0 = *(const float4*)&dscp[0][ml * 8 + jb * 4];
                float4 d1 = *(const float4*)&dscp[1][ml * 8 + jb * 4];
                float4 d2 = *(const float4*)&dscp[2][ml * 8 + jb * 4];
                float4 d3 = *(const float4*)&dscp[3][ml * 8 + jb * 4];
                dsc8[jb*4+0] = d0.x + d1.x + d2.x + d3.x + bw8[jb*4+0];
                dsc8[jb*4+1] = d0.y + d1.y + d2.y + d3.y + bw8[jb*4+1];
                dsc8[jb*4+2] = d0.z + d1.z + d2.z + d3.z + bw8[jb*4+2];
                dsc8[jb*4+3] = d0.w + d1.w + d2.w + d3.w + bw8[jb*4+3];
            }
            float sum_ev = 0.f, sum_yg = 0.f;
            #pragma unroll 4
            for (int q = 0; q < 16; ++q) {
                int row = aw * 32 + 2 * q + hl;
                uint4 u = *(const uint4*)&ue_lds[row * 256 + ml * 8];
                hf2 p0 = __builtin_bit_cast(hf2, u.x);
                hf2 p1 = __builtin_bit_cast(hf2, u.y);
                hf2 p2 = __builtin_bit_cast(hf2, u.z);
                hf2 p3 = __builtin_bit_cast(hf2, u.w);
                float pl;
                pl  = fast_tanh(dsc8[0] + (float)p0.x) * wv8[0];
                pl += fast_tanh(dsc8[1] + (float)p0.y) * wv8[1];
                pl += fast_tanh(dsc8[2] + (float)p1.x) * wv8[2];
                pl += fast_tanh(dsc8[3] + (float)p1.y) * wv8[3];
                pl += fast_tanh(dsc8[4] + (float)p2.x) * wv8[4];
                pl += fast_tanh(dsc8[5] + (float)p2.y) * wv8[5];
                pl += fast_tanh(dsc8[6] + (float)p3.x) * wv8[6];
                pl += fast_tanh(dsc8[7] + (float)p3.y) * wv8[7];
                #pragma unroll
                for (int mm = 16; mm >= 1; mm >>= 1) pl += __shfl_xor(pl, mm, 64);
                if (ml == 0) {
                    float ev = exp2f((pl + bv0) * 1.442695041f);
                    el_lds[row] = ev;
                    sum_ev += ev;
                    sum_yg += ev * g_lds[row];
                }
            }
            sum_ev += __shfl_xor(sum_ev, 32, 64);
            sum_yg += __shfl_xor(sum_yg, 32, 64);
            if (lane == 0) { sred[aw] = sum_ev; yred[aw] = sum_yg; }
        }
        __syncthreads();                               // Z
    }

    // ---- epilogue: final ctx from el(254) + fp32 enc, then output head ----
    {
        float S;
        {
            float4 sa = *(const float4*)&sred[0], sb = *(const float4*)&sred[4];
            S = sa.x + sa.y + sa.z + sa.w + sb.x + sb.y + sb.z + sb.w;
        }
        float a0 = 0.f, a1 = 0.f, a2 = 0.f, a3 = 0.f;
        for (int i = 0; i < 16; ++i) {
            int tp = wave * 16 + i;
            float w = el_lds[tp];
            float4 e4 = *(const float4*)&encB[(size_t)tp * 256 + lane * 4];
            a0 += w * e4.x; a1 += w * e4.y; a2 += w * e4.z; a3 += w * e4.w;
        }
        atomicAdd(&ctx_lds[lane * 4 + 0], a0);
        atomicAdd(&ctx_lds[lane * 4 + 1], a1);
        atomicAdd(&ctx_lds[lane * 4 + 2], a2);
        atomicAdd(&ctx_lds[lane * 4 + 3], a3);
        __syncthreads();

        float qp = 0.f;
        if (tid < 256) {
            float ctx = ctx_lds[tid] * __builtin_amdgcn_rcpf(S);
            qp = h_lds[tid] * Wvb[tid] + ctx * Wvb[256 + tid];
        }
        if (wave < 4) {
            #pragma unroll
            for (int mm = 32; mm >= 1; mm >>= 1) qp += __shfl_xor(qp, mm, 64);
            if (lane == 0) ya[wave] = qp;
        }
        __syncthreads();
        if (tid < 256) {
            float qv = ya[0] + ya[1] + ya[2] + ya[3] + bvb[0];
            out[b * 256 + tid] = qv * Wwb[tid] + bwb[tid];
        }
    }
}

extern "C" void kernel_launch(void* const* d_in, const int* in_sizes, int n_in,
                              void* d_out, int out_size, void* d_ws, size_t ws_size,
                              hipStream_t stream) {
    const float* data = (const float*)d_in[0];
    const float* enc  = (const float*)d_in[1];
    const float* h0   = (const float*)d_in[2];
    const float* s0   = (const float*)d_in[3];
    const float* Wd   = (const float*)d_in[4];
    const float* bd   = (const float*)d_in[5];
    const float* Wk   = (const float*)d_in[6];
    const float* Wr   = (const float*)d_in[7];
    const float* bl   = (const float*)d_in[8];
    const float* Ww   = (const float*)d_in[9];
    const float* bw   = (const float*)d_in[10];
    const float* Wu   = (const float*)d_in[11];
    const float* bu   = (const float*)d_in[12];
    const float* Wv   = (const float*)d_in[13];
    const float* bv   = (const float*)d_in[14];
    const float* Wvb  = (const float*)d_in[15];
    const float* bvb  = (const float*)d_in[16];
    const float* Wwb  = (const float*)d_in[17];
    const float* bwb  = (const float*)d_in[18];

    _Float16* Ue16 = (_Float16*)d_ws;                                 // 32 MB
    uint4* Wsz  = (uint4*)((char*)d_ws + (32ull << 20));              // 512 KB
    uint4* Wwsz = (uint4*)((char*)d_ws + (32ull << 20) + (512ull << 10)); // 256 KB
    float* out = (float*)d_out;

    hipLaunchKernelGGL(ue_gemm, dim3((B * T) / 32), dim3(256), 0, stream,
                       enc, Wu, bu, Ue16);
    hipLaunchKernelGGL(wr_cvt, dim3(128), dim3(256), 0, stream, Wr, Wsz);
    hipLaunchKernelGGL(ww_cvt, dim3(64), dim3(256), 0, stream, Ww, Wwsz);
    hipLaunchKernelGGL(decoder_scan, dim3(B), dim3(NT), 0, stream,
                       data, h0, s0, Wd, bd, Wk, bl, bw,
                       Wv, bv, Wvb, bvb, Wwb, bwb,
                       enc, Ue16, Wsz, Wwsz, out);
}

// Round 6
// 3758.479 us; speedup vs baseline: 3.3178x; 1.0697x over previous
//
#include <hip/hip_runtime.h>
#include <hip/hip_bf16.h>

#define B 256
#define T 256
#define M 256
#define P 256
#define TSTEPS 255
#define NT 1024

typedef unsigned int uint;
typedef _Float16 hf2 __attribute__((ext_vector_type(2)));

__device__ __forceinline__ float fast_tanh(float x) {
    float e = exp2f(x * 2.885390082f);             // e^(2x)
    return 1.f - 2.f * __builtin_amdgcn_rcpf(e + 1.f);
}
__device__ __forceinline__ float fast_sigmoid(float x) {
    float e = exp2f(-x * 1.442695041f);            // e^(-x)
    return __builtin_amdgcn_rcpf(1.f + e);
}

#if defined(__has_builtin)
#if __has_builtin(__builtin_amdgcn_fdot2)
#define HAVE_FDOT2 1
#endif
#endif

__device__ __forceinline__ float dot2(uint a, uint b, float c) {
#ifdef HAVE_FDOT2
    return __builtin_amdgcn_fdot2(__builtin_bit_cast(hf2, a),
                                  __builtin_bit_cast(hf2, b), c, false);
#else
    hf2 x = __builtin_bit_cast(hf2, a), y = __builtin_bit_cast(hf2, b);
    return c + (float)x.x * (float)y.x + (float)x.y * (float)y.y;
#endif
}

__device__ __forceinline__ uint pk16(float a, float b) {
    return __builtin_bit_cast(uint, __builtin_amdgcn_cvt_pkrtz(a, b));
}

// ---------------- Ue16 = f16(encoder_h @ Wu + bu) ----------------
__global__ __launch_bounds__(256) void ue_gemm(
    const float* __restrict__ enc, const float* __restrict__ Wu,
    const float* __restrict__ bu, _Float16* __restrict__ Ue16)
{
    __shared__ float At[32][256];
    const int r0 = blockIdx.x * 32;
    const int tid = threadIdx.x;

    #pragma unroll 4
    for (int i = 0; i < 32; ++i)
        At[i][tid] = enc[(size_t)(r0 + i) * 256 + tid];
    __syncthreads();

    float acc[32];
    #pragma unroll
    for (int r = 0; r < 32; ++r) acc[r] = 0.f;

    for (int k = 0; k < 256; k += 4) {
        float w0 = Wu[(size_t)(k + 0) * 256 + tid];
        float w1 = Wu[(size_t)(k + 1) * 256 + tid];
        float w2 = Wu[(size_t)(k + 2) * 256 + tid];
        float w3 = Wu[(size_t)(k + 3) * 256 + tid];
        #pragma unroll
        for (int r = 0; r < 32; ++r) {
            float4 a4 = *(const float4*)&At[r][k];
            acc[r] += a4.x * w0 + a4.y * w1 + a4.z * w2 + a4.w * w3;
        }
    }
    float bub = bu[tid];
    #pragma unroll 4
    for (int r = 0; r < 32; ++r)
        Ue16[(size_t)(r0 + r) * 256 + tid] = (_Float16)(acc[r] + bub);
}

// ---- Wsz[kc*1024+c] = uint4 of f16 pairs of Wr[kc*8+j][c], j=0..7 ----
__global__ __launch_bounds__(256) void wr_cvt(
    const float* __restrict__ Wr, uint4* __restrict__ Wsz)
{
    int i = blockIdx.x * 256 + threadIdx.x;        // 32768
    int kc = i >> 10, c = i & 1023;
    const float* s = Wr + (size_t)kc * 8 * 1024 + c;
    uint4 o;
    o.x = pk16(s[0 * 1024], s[1 * 1024]);
    o.y = pk16(s[2 * 1024], s[3 * 1024]);
    o.z = pk16(s[4 * 1024], s[5 * 1024]);
    o.w = pk16(s[6 * 1024], s[7 * 1024]);
    Wsz[i] = o;
}

// ---- Wwsz[kk*256+m] = uint4 of f16 pairs of Ww[kk*8+j][m], j=0..7 ----
__global__ __launch_bounds__(256) void ww_cvt(
    const float* __restrict__ Ww, uint4* __restrict__ Wwsz)
{
    int i = blockIdx.x * 256 + threadIdx.x;        // 16384
    int kk = i >> 8, m = i & 255;
    const float* s = Ww + (size_t)kk * 8 * 256 + m;
    uint4 o;
    o.x = pk16(s[0 * 256], s[1 * 256]);
    o.y = pk16(s[2 * 256], s[3 * 256]);
    o.z = pk16(s[4 * 256], s[5 * 256]);
    o.w = pk16(s[6 * 256], s[7 * 256]);
    Wwsz[i] = o;
}

// ---------------- main scan: one block (1024 thr) per batch element ----------------
// Waves 0-7 (G): stream Wr, compute acc_{t+1}. Waves 8-15 (A): D_t then E_t.
__global__ __launch_bounds__(NT, 4) void decoder_scan(
    const float* __restrict__ data,
    const float* __restrict__ h0,  const float* __restrict__ s0,
    const float* __restrict__ Wd,  const float* __restrict__ bd,
    const float* __restrict__ Wk,  const float* __restrict__ bl,
    const float* __restrict__ bw,
    const float* __restrict__ Wv,  const float* __restrict__ bv,
    const float* __restrict__ Wvb, const float* __restrict__ bvb,
    const float* __restrict__ Wwb, const float* __restrict__ bwb,
    const float* __restrict__ enc,
    const _Float16* __restrict__ Ue16g,
    const uint4* __restrict__ Wsz, const uint4* __restrict__ Wwsz,
    float* __restrict__ out)
{
    const int b    = blockIdx.x;
    const int tid  = threadIdx.x;
    const int lane = tid & 63;
    const int wave = tid >> 6;          // 0..15

    __shared__ _Float16 ue_lds[T * M];  // 128 KB, chunk-swizzled
    __shared__ float h_lds[P], s_lds[P];
    __shared__ uint  h2_lds[P / 2], s2_lds[P / 2];
    __shared__ float z_lds[4 * P];
    __shared__ float dsc_lds[M];
    __shared__ float el_lds[T];
    __shared__ float g_lds[T];
    __shared__ float ctx_lds[M];
    __shared__ float wv_lds[M];
    __shared__ __align__(16) float sred[8], yred[8];
    __shared__ float ya[4];
    __shared__ float data_lds[TSTEPS + 1];

    // ---- stage Ue into LDS, chunk-swizzled: phys = (lin&16) | ((lin ^ (2r+(lin>>4)))&15)
    {
        const uint4* src = (const uint4*)(Ue16g + (size_t)b * T * M);
        uint4* dst = (uint4*)ue_lds;
        #pragma unroll
        for (int i = 0; i < 8; ++i) {
            int g = tid + i * NT;
            uint4 v = src[g];
            int r = g >> 5, lin = g & 31;
            int phys = (lin & 16) | ((lin ^ (2 * r + (lin >> 4))) & 15);
            dst[(r << 5) + phys] = v;
        }
    }
    if (tid < 256) {
        float hv = h0[b * 256 + tid], sv = s0[b * 256 + tid];
        h_lds[tid] = hv; s_lds[tid] = sv; ctx_lds[tid] = 0.f;
        wv_lds[tid] = Wv[tid];
        float hv1 = __shfl_down(hv, 1, 64);
        float sv1 = __shfl_down(sv, 1, 64);
        if (!(tid & 1)) {
            h2_lds[tid >> 1] = pk16(hv, hv1);
            s2_lds[tid >> 1] = pk16(sv, sv1);
        }
    }
    if (tid < 8) { sred[tid] = 1.f; yred[tid] = 0.f; }   // ctx_0 = 0
    if (tid < TSTEPS) data_lds[tid] = data[b * TSTEPS + tid];

    // ---- constants ----
    const float Wd0 = Wd[0], bd0 = bd[0], bv0 = bv[0];
    const int   gate = tid & 3, uu = tid >> 2;
    const int   cp = gate * 256 + uu;
    const float wkp = Wk[cp], blp = bl[cp];

    const float* encB = enc + (size_t)b * T * M;

    // ---- g[tp] = <enc[tp,:], Wd[1:]>  (step-invariant y projection) ----
    {
        float w0 = Wd[1 + lane * 4], w1 = Wd[2 + lane * 4];
        float w2 = Wd[3 + lane * 4], w3 = Wd[4 + lane * 4];
        for (int i = 0; i < 16; ++i) {
            int tp = wave * 16 + i;
            float4 e4 = *(const float4*)&encB[(size_t)tp * 256 + lane * 4];
            float p = e4.x * w0 + e4.y * w1 + e4.z * w2 + e4.w * w3;
            #pragma unroll
            for (int mm = 32; mm >= 1; mm >>= 1) p += __shfl_xor(p, mm, 64);
            if (lane == 0) g_lds[tp] = p;
        }
    }
    __syncthreads();

    const uint4* h2u4 = (const uint4*)h2_lds;
    const uint4* s2u4 = (const uint4*)s2_lds;

    // ---- prologue: acc_0 = Wr·h_0 into z_lds (1 col per thread) ----
    {
        const uint4* wc = Wsz + tid;
        float acc = 0.f;
        #pragma unroll 4
        for (int kc = 0; kc < 32; ++kc) {
            uint4 w = wc[kc << 10];
            uint4 h = h2u4[kc];
            acc = dot2(w.x, h.x, acc); acc = dot2(w.y, h.y, acc);
            acc = dot2(w.z, h.z, acc); acc = dot2(w.w, h.w, acc);
        }
        z_lds[tid] = acc;
    }
    __syncthreads();

    // ---- per-group constants ----
    const int aw  = wave - 8;                       // A-wave 0..7
    const int aid = (tid >= 512) ? (tid - 512) : 0; // A-thread 0..511
    const int dm  = aid >> 1;                       // D: m-col / E: row
    const int dkh = aid & 1;                        // D: h/s half, E: m-half
    const int ekey = aid & 15;                      // ue swizzle key = (2r+mh)&15
    const float bwm = bw[dm];
    const uint4* wwp  = Wwsz + (dkh << 13) + dm;    // (dkh*32)*256 + m
    const uint4* uecT = (const uint4*)ue_lds + (aid << 4);  // row base + half
    const float4* dsc4T = (const float4*)dsc_lds + (dkh << 5);
    const float4* wv4T  = (const float4*)wv_lds  + (dkh << 5);
    const uint4* wcA = Wsz + tid;
    const uint4* wcB = Wsz + tid + 512;

    float accA = 0.f, accB = 0.f;

    for (int t = 0; t < TSTEPS; ++t) {
        // ---- P1: ys; z = acc + ys*wk + bl; quad-shfl LSTM gates ----
        {
            float4 sa = *(const float4*)&sred[0], sb = *(const float4*)&sred[4];
            float4 yaa = *(const float4*)&yred[0], yab = *(const float4*)&yred[4];
            float S = sa.x + sa.y + sa.z + sa.w + sb.x + sb.y + sb.z + sb.w;
            float Y = yaa.x + yaa.y + yaa.z + yaa.w + yab.x + yab.y + yab.z + yab.w;
            float ys = Y * __builtin_amdgcn_rcpf(S) + data_lds[t] * Wd0 + bd0;
            float zc = z_lds[cp] + ys * wkp + blp;
            float nl = (gate == 2) ? fast_tanh(zc) : fast_sigmoid(zc);
            float n1 = __shfl_xor(nl, 1, 64);
            float n2 = __shfl_xor(nl, 2, 64);
            float n3 = __shfl_xor(nl, 3, 64);
            float hn = 0.f, snv = 0.f;
            if (gate == 0) {                        // nl=sig_i n1=sig_f n2=tanh_g n3=sig_o
                float s_old = s_lds[uu];
                snv = n1 * s_old + nl * n2;
                hn  = n3 * fast_tanh(snv);
                s_lds[uu] = snv; h_lds[uu] = hn;
            }
            float hn4 = __shfl_down(hn, 4, 64);
            float sn4 = __shfl_down(snv, 4, 64);
            if ((tid & 7) == 0) {
                h2_lds[uu >> 1] = pk16(hn, hn4);
                s2_lds[uu >> 1] = pk16(snv, sn4);
            }
        }
        __syncthreads();                             // X: h_{t+1} ready

        // ---- P2: G: acc kc 0..15   |   A: D_t (dsc full-K, pair combine) ----
        if (wave < 8) {
            accA = 0.f; accB = 0.f;
            #pragma unroll 4
            for (int kc = 0; kc < 16; ++kc) {
                uint4 wA = wcA[kc << 10], wB = wcB[kc << 10];
                uint4 h = h2u4[kc];
                accA = dot2(wA.x, h.x, accA); accA = dot2(wA.y, h.y, accA);
                accA = dot2(wA.z, h.z, accA); accA = dot2(wA.w, h.w, accA);
                accB = dot2(wB.x, h.x, accB); accB = dot2(wB.y, h.y, accB);
                accB = dot2(wB.z, h.z, accB); accB = dot2(wB.w, h.w, accB);
            }
        } else {
            const uint4* cat4 = dkh ? s2u4 : h2u4;
            float a = 0.f;
            #pragma unroll 4
            for (int i = 0; i < 32; ++i) {
                uint4 w = wwp[i << 8];
                uint4 c = cat4[i];
                a = dot2(w.x, c.x, a); a = dot2(w.y, c.y, a);
                a = dot2(w.z, c.z, a); a = dot2(w.w, c.w, a);
            }
            a += __shfl_xor(a, 1, 64);
            if (!dkh) dsc_lds[dm] = a + bwm;
        }
        __syncthreads();                             // Y: dsc ready

        // ---- P3: G: acc kc 16..31 + write z   |   A: E_t (row-local) ----
        if (wave < 8) {
            #pragma unroll 4
            for (int kc = 16; kc < 32; ++kc) {
                uint4 wA = wcA[kc << 10], wB = wcB[kc << 10];
                uint4 h = h2u4[kc];
                accA = dot2(wA.x, h.x, accA); accA = dot2(wA.y, h.y, accA);
                accA = dot2(wA.z, h.z, accA); accA = dot2(wA.w, h.w, accA);
                accB = dot2(wB.x, h.x, accB); accB = dot2(wB.y, h.y, accB);
                accB = dot2(wB.z, h.z, accB); accB = dot2(wB.w, h.w, accB);
            }
            z_lds[tid] = accA; z_lds[tid + 512] = accB;
        } else {
            float pl = 0.f;
            #pragma unroll 4
            for (int jj = 0; jj < 16; ++jj) {
                uint4 u = uecT[jj ^ ekey];
                float4 d0 = dsc4T[jj * 2], d1 = dsc4T[jj * 2 + 1];
                float4 w0 = wv4T[jj * 2],  w1 = wv4T[jj * 2 + 1];
                hf2 p0 = __builtin_bit_cast(hf2, u.x);
                hf2 p1 = __builtin_bit_cast(hf2, u.y);
                hf2 p2 = __builtin_bit_cast(hf2, u.z);
                hf2 p3 = __builtin_bit_cast(hf2, u.w);
                pl += fast_tanh(d0.x + (float)p0.x) * w0.x;
                pl += fast_tanh(d0.y + (float)p0.y) * w0.y;
                pl += fast_tanh(d0.z + (float)p1.x) * w0.z;
                pl += fast_tanh(d0.w + (float)p1.y) * w0.w;
                pl += fast_tanh(d1.x + (float)p2.x) * w1.x;
                pl += fast_tanh(d1.y + (float)p2.y) * w1.y;
                pl += fast_tanh(d1.z + (float)p3.x) * w1.z;
                pl += fast_tanh(d1.w + (float)p3.y) * w1.w;
            }
            pl += __shfl_xor(pl, 1, 64);             // merge m-halves
            float ev = exp2f((pl + bv0) * 1.442695041f);
            if (!dkh) el_lds[dm] = ev;               // dm = row here
            float yg = ev * g_lds[dm];
            #pragma unroll
            for (int mm = 2; mm <= 32; mm <<= 1) {   // rows counted once (even lanes)
                ev += __shfl_xor(ev, mm, 64);
                yg += __shfl_xor(yg, mm, 64);
            }
            if (lane == 0) { sred[aw] = ev; yred[aw] = yg; }
        }
        __syncthreads();                             // Z
    }

    // ---- epilogue: final ctx from el(254) + fp32 enc, then output head ----
    {
        float S;
        {
            float4 sa = *(const float4*)&sred[0], sb = *(const float4*)&sred[4];
            S = sa.x + sa.y + sa.z + sa.w + sb.x + sb.y + sb.z + sb.w;
        }
        float a0 = 0.f, a1 = 0.f, a2 = 0.f, a3 = 0.f;
        for (int i = 0; i < 16; ++i) {
            int tp = wave * 16 + i;
            float w = el_lds[tp];
            float4 e4 = *(const float4*)&encB[(size_t)tp * 256 + lane * 4];
            a0 += w * e4.x; a1 += w * e4.y; a2 += w * e4.z; a3 += w * e4.w;
        }
        atomicAdd(&ctx_lds[lane * 4 + 0], a0);
        atomicAdd(&ctx_lds[lane * 4 + 1], a1);
        atomicAdd(&ctx_lds[lane * 4 + 2], a2);
        atomicAdd(&ctx_lds[lane * 4 + 3], a3);
        __syncthreads();

        float qp = 0.f;
        if (tid < 256) {
            float ctx = ctx_lds[tid] * __builtin_amdgcn_rcpf(S);
            qp = h_lds[tid] * Wvb[tid] + ctx * Wvb[256 + tid];
        }
        if (wave < 4) {
            #pragma unroll
            for (int mm = 32; mm >= 1; mm >>= 1) qp += __shfl_xor(qp, mm, 64);
            if (lane == 0) ya[wave] = qp;
        }
        __syncthreads();
        if (tid < 256) {
            float qv = ya[0] + ya[1] + ya[2] + ya[3] + bvb[0];
            out[b * 256 + tid] = qv * Wwb[tid] + bwb[tid];
        }
    }
}

extern "C" void kernel_launch(void* const* d_in, const int* in_sizes, int n_in,
                              void* d_out, int out_size, void* d_ws, size_t ws_size,
                              hipStream_t stream) {
    const float* data = (const float*)d_in[0];
    const float* enc  = (const float*)d_in[1];
    const float* h0   = (const float*)d_in[2];
    const float* s0   = (const float*)d_in[3];
    const float* Wd   = (const float*)d_in[4];
    const float* bd   = (const float*)d_in[5];
    const float* Wk   = (const float*)d_in[6];
    const float* Wr   = (const float*)d_in[7];
    const float* bl   = (const float*)d_in[8];
    const float* Ww   = (const float*)d_in[9];
    const float* bw   = (const float*)d_in[10];
    const float* Wu   = (const float*)d_in[11];
    const float* bu   = (const float*)d_in[12];
    const float* Wv   = (const float*)d_in[13];
    const float* bv   = (const float*)d_in[14];
    const float* Wvb  = (const float*)d_in[15];
    const float* bvb  = (const float*)d_in[16];
    const float* Wwb  = (const float*)d_in[17];
    const float* bwb  = (const float*)d_in[18];

    _Float16* Ue16 = (_Float16*)d_ws;                                 // 32 MB
    uint4* Wsz  = (uint4*)((char*)d_ws + (32ull << 20));              // 512 KB
    uint4* Wwsz = (uint4*)((char*)d_ws + (32ull << 20) + (512ull << 10)); // 256 KB
    float* out = (float*)d_out;

    hipLaunchKernelGGL(ue_gemm, dim3((B * T) / 32), dim3(256), 0, stream,
                       enc, Wu, bu, Ue16);
    hipLaunchKernelGGL(wr_cvt, dim3(128), dim3(256), 0, stream, Wr, Wsz);
    hipLaunchKernelGGL(ww_cvt, dim3(64), dim3(256), 0, stream, Ww, Wwsz);
    hipLaunchKernelGGL(decoder_scan, dim3(B), dim3(NT), 0, stream,
                       data, h0, s0, Wd, bd, Wk, bl, bw,
                       Wv, bv, Wvb, bvb, Wwb, bwb,
                       enc, Ue16, Wsz, Wwsz, out);
}

// Round 7
// 2848.055 us; speedup vs baseline: 4.3784x; 1.3197x over previous
//
#include <hip/hip_runtime.h>
#include <hip/hip_bf16.h>

#define B 256
#define T 256
#define M 256
#define P 256
#define TSTEPS 255
#define NT 1024

typedef unsigned int uint;
typedef _Float16 hf2 __attribute__((ext_vector_type(2)));

__device__ __forceinline__ float fast_tanh(float x) {
    float e = exp2f(x * 2.885390082f);             // e^(2x)
    return 1.f - 2.f * __builtin_amdgcn_rcpf(e + 1.f);
}
__device__ __forceinline__ float fast_sigmoid(float x) {
    float e = exp2f(-x * 1.442695041f);            // e^(-x)
    return __builtin_amdgcn_rcpf(1.f + e);
}

#if defined(__has_builtin)
#if __has_builtin(__builtin_amdgcn_fdot2)
#define HAVE_FDOT2 1
#endif
#endif

__device__ __forceinline__ float dot2(uint a, uint b, float c) {
#ifdef HAVE_FDOT2
    return __builtin_amdgcn_fdot2(__builtin_bit_cast(hf2, a),
                                  __builtin_bit_cast(hf2, b), c, false);
#else
    hf2 x = __builtin_bit_cast(hf2, a), y = __builtin_bit_cast(hf2, b);
    return c + (float)x.x * (float)y.x + (float)x.y * (float)y.y;
#endif
}

__device__ __forceinline__ uint pk16(float a, float b) {
    return __builtin_bit_cast(uint, __builtin_amdgcn_cvt_pkrtz(a, b));
}

// ---------------- EU = f16(exp(encoder_h @ Wu + bu)) ----------------
__global__ __launch_bounds__(256) void ue_gemm(
    const float* __restrict__ enc, const float* __restrict__ Wu,
    const float* __restrict__ bu, _Float16* __restrict__ Ue16)
{
    __shared__ float At[32][256];
    const int r0 = blockIdx.x * 32;
    const int tid = threadIdx.x;

    #pragma unroll 4
    for (int i = 0; i < 32; ++i)
        At[i][tid] = enc[(size_t)(r0 + i) * 256 + tid];
    __syncthreads();

    float acc[32];
    #pragma unroll
    for (int r = 0; r < 32; ++r) acc[r] = 0.f;

    for (int k = 0; k < 256; k += 4) {
        float w0 = Wu[(size_t)(k + 0) * 256 + tid];
        float w1 = Wu[(size_t)(k + 1) * 256 + tid];
        float w2 = Wu[(size_t)(k + 2) * 256 + tid];
        float w3 = Wu[(size_t)(k + 3) * 256 + tid];
        #pragma unroll
        for (int r = 0; r < 32; ++r) {
            float4 a4 = *(const float4*)&At[r][k];
            acc[r] += a4.x * w0 + a4.y * w1 + a4.z * w2 + a4.w * w3;
        }
    }
    float bub = bu[tid];
    #pragma unroll 4
    for (int r = 0; r < 32; ++r)
        Ue16[(size_t)(r0 + r) * 256 + tid] =
            (_Float16)exp2f(1.442695041f * (acc[r] + bub));   // e^{u}
}

// ---- Wsz[kc*1024+c] = uint4 of f16 pairs of Wr[kc*8+j][c], j=0..7 ----
__global__ __launch_bounds__(256) void wr_cvt(
    const float* __restrict__ Wr, uint4* __restrict__ Wsz)
{
    int i = blockIdx.x * 256 + threadIdx.x;        // 32768
    int kc = i >> 10, c = i & 1023;
    const float* s = Wr + (size_t)kc * 8 * 1024 + c;
    uint4 o;
    o.x = pk16(s[0 * 1024], s[1 * 1024]);
    o.y = pk16(s[2 * 1024], s[3 * 1024]);
    o.z = pk16(s[4 * 1024], s[5 * 1024]);
    o.w = pk16(s[6 * 1024], s[7 * 1024]);
    Wsz[i] = o;
}

// ---- Wwsz[kk*256+m] = uint4 of f16 pairs of Ww[kk*8+j][m], j=0..7 ----
__global__ __launch_bounds__(256) void ww_cvt(
    const float* __restrict__ Ww, uint4* __restrict__ Wwsz)
{
    int i = blockIdx.x * 256 + threadIdx.x;        // 16384
    int kk = i >> 8, m = i & 255;
    const float* s = Ww + (size_t)kk * 8 * 256 + m;
    uint4 o;
    o.x = pk16(s[0 * 256], s[1 * 256]);
    o.y = pk16(s[2 * 256], s[3 * 256]);
    o.z = pk16(s[4 * 256], s[5 * 256]);
    o.w = pk16(s[6 * 256], s[7 * 256]);
    Wwsz[i] = o;
}

// ---------------- main scan: one block (1024 thr) per batch element ----------------
// Waves 0-7 (G): stream Wr, compute acc_{t+1}. Waves 8-15 (A): D_t then E_t.
// E uses tanh(x) = 1 - 2/( (e^d * e^u)^2 + 1 ) with e^u (EU) precomputed and
// e^d (ED) computed once per step; softmax-constant terms cancel and are dropped.
__global__ __launch_bounds__(NT, 4) void decoder_scan(
    const float* __restrict__ data,
    const float* __restrict__ h0,  const float* __restrict__ s0,
    const float* __restrict__ Wd,  const float* __restrict__ bd,
    const float* __restrict__ Wk,  const float* __restrict__ bl,
    const float* __restrict__ bw,
    const float* __restrict__ Wv,  const float* __restrict__ bv,
    const float* __restrict__ Wvb, const float* __restrict__ bvb,
    const float* __restrict__ Wwb, const float* __restrict__ bwb,
    const float* __restrict__ enc,
    const _Float16* __restrict__ Ue16g,
    const uint4* __restrict__ Wsz, const uint4* __restrict__ Wwsz,
    float* __restrict__ out)
{
    const int b    = blockIdx.x;
    const int tid  = threadIdx.x;
    const int lane = tid & 63;
    const int wave = tid >> 6;          // 0..15

    __shared__ _Float16 ue_lds[T * M];          // 128 KB EU, chunk-swizzled
    __shared__ float h_lds[P], s_lds[P];
    __shared__ __align__(16) uint hs2[128 + 4 + 128];   // h2 @0, s2 @132 (+1 bank group)
    __shared__ float z_lds[4 * 257];            // padded: gate*257 + uu
    __shared__ __align__(16) uint  edup[2][132];        // ED f16 pairs, dup copies
    __shared__ __align__(16) float wv2dup[2][264];      // 2*Wv f32, dup copies
    __shared__ float el_lds[T];
    __shared__ float g_lds[T];
    __shared__ float ctx_lds[M];
    __shared__ __align__(16) float sred[8], yred[8];
    __shared__ float ya[4];
    __shared__ float data_lds[TSTEPS + 1];

    uint* h2_lds = hs2;
    uint* s2_lds = hs2 + 132;

    // ---- stage EU into LDS, chunk-swizzled: phys = (lin&16) | ((lin ^ (2r+(lin>>4)))&15)
    {
        const uint4* src = (const uint4*)(Ue16g + (size_t)b * T * M);
        uint4* dst = (uint4*)ue_lds;
        #pragma unroll
        for (int i = 0; i < 8; ++i) {
            int g = tid + i * NT;
            uint4 v = src[g];
            int r = g >> 5, lin = g & 31;
            int phys = (lin & 16) | ((lin ^ (2 * r + (lin >> 4))) & 15);
            dst[(r << 5) + phys] = v;
        }
    }
    if (tid < 256) {
        float hv = h0[b * 256 + tid], sv = s0[b * 256 + tid];
        h_lds[tid] = hv; s_lds[tid] = sv; ctx_lds[tid] = 0.f;
        float w2 = 2.f * Wv[tid];
        wv2dup[0][tid] = w2; wv2dup[1][tid] = w2;
        float hv1 = __shfl_down(hv, 1, 64);
        float sv1 = __shfl_down(sv, 1, 64);
        if (!(tid & 1)) {
            h2_lds[tid >> 1] = pk16(hv, hv1);
            s2_lds[tid >> 1] = pk16(sv, sv1);
        }
    }
    if (tid < 8) { sred[tid] = 1.f; yred[tid] = 0.f; }   // ctx_0 = 0
    if (tid < TSTEPS) data_lds[tid] = data[b * TSTEPS + tid];

    // ---- constants ----
    const float Wd0 = Wd[0], bd0 = bd[0];
    const int   gate = tid & 3, uu = tid >> 2;
    const int   cp  = gate * 256 + uu;          // logical z column
    const int   cpi = gate * 257 + uu;          // padded LDS index
    const float wkp = Wk[cp], blp = bl[cp];

    const float* encB = enc + (size_t)b * T * M;

    // ---- g[tp] = <enc[tp,:], Wd[1:]>  (step-invariant y projection) ----
    {
        float w0 = Wd[1 + lane * 4], w1 = Wd[2 + lane * 4];
        float w2 = Wd[3 + lane * 4], w3 = Wd[4 + lane * 4];
        for (int i = 0; i < 16; ++i) {
            int tp = wave * 16 + i;
            float4 e4 = *(const float4*)&encB[(size_t)tp * 256 + lane * 4];
            float p = e4.x * w0 + e4.y * w1 + e4.z * w2 + e4.w * w3;
            #pragma unroll
            for (int mm = 32; mm >= 1; mm >>= 1) p += __shfl_xor(p, mm, 64);
            if (lane == 0) g_lds[tp] = p;
        }
    }
    __syncthreads();

    const uint4* h2u4 = (const uint4*)h2_lds;
    const uint4* s2u4 = (const uint4*)s2_lds;

    // ---- prologue: acc_0 = Wr·h_0 into z_lds (1 col per thread) ----
    {
        const uint4* wc = Wsz + tid;
        float acc = 0.f;
        #pragma unroll 4
        for (int kc = 0; kc < 32; ++kc) {
            uint4 w = wc[kc << 10];
            uint4 h = h2u4[kc];
            acc = dot2(w.x, h.x, acc); acc = dot2(w.y, h.y, acc);
            acc = dot2(w.z, h.z, acc); acc = dot2(w.w, h.w, acc);
        }
        z_lds[(tid >> 8) * 257 + (tid & 255)] = acc;
    }
    __syncthreads();

    // ---- per-group constants ----
    const int aw  = wave - 8;                       // A-wave 0..7
    const int aid = (tid >= 512) ? (tid - 512) : 0; // A-thread 0..511
    const int dm  = aid >> 1;                       // D: m-col / E: row
    const int dkh = aid & 1;                        // D: h/s K-half, E: m-half
    const int ekey = aid & 15;                      // ue swizzle key
    const float bwm = bw[dm];
    const uint4* wwp  = Wwsz + (dkh << 13) + dm;    // (dkh*32)*256 + m
    const uint4* uecT = (const uint4*)ue_lds + (aid << 4);
    const uint4*  edT = (const uint4*)(&edup[dkh][0]) + (dkh << 4);   // +dkh*64 uints
    const float4* wvT = (const float4*)(&wv2dup[dkh][0]) + (dkh << 5);// +dkh*128 f
    const uint4* wcA = Wsz + tid;
    const uint4* wcB = Wsz + tid + 512;

    float accA = 0.f, accB = 0.f;

    for (int t = 0; t < TSTEPS; ++t) {
        // ---- P1: ys; z = acc + ys*wk + bl; quad-shfl LSTM gates ----
        {
            float4 sa = *(const float4*)&sred[0], sb = *(const float4*)&sred[4];
            float4 yaa = *(const float4*)&yred[0], yab = *(const float4*)&yred[4];
            float S = sa.x + sa.y + sa.z + sa.w + sb.x + sb.y + sb.z + sb.w;
            float Y = yaa.x + yaa.y + yaa.z + yaa.w + yab.x + yab.y + yab.z + yab.w;
            float ys = Y * __builtin_amdgcn_rcpf(S) + data_lds[t] * Wd0 + bd0;
            float zc = z_lds[cpi] + ys * wkp + blp;
            float nl = (gate == 2) ? fast_tanh(zc) : fast_sigmoid(zc);
            float n1 = __shfl_xor(nl, 1, 64);
            float n2 = __shfl_xor(nl, 2, 64);
            float n3 = __shfl_xor(nl, 3, 64);
            float hn = 0.f, snv = 0.f;
            if (gate == 0) {                        // nl=sig_i n1=sig_f n2=tanh_g n3=sig_o
                float s_old = s_lds[uu];
                snv = n1 * s_old + nl * n2;
                hn  = n3 * fast_tanh(snv);
                s_lds[uu] = snv; h_lds[uu] = hn;
            }
            float hn4 = __shfl_down(hn, 4, 64);
            float sn4 = __shfl_down(snv, 4, 64);
            if ((tid & 7) == 0) {
                h2_lds[uu >> 1] = pk16(hn, hn4);
                s2_lds[uu >> 1] = pk16(snv, sn4);
            }
        }
        __syncthreads();                             // X: h_{t+1} ready

        // ---- P2: G: acc kc 0..15   |   A: D_t -> ED (f16 e^{dsc+bw}) ----
        if (wave < 8) {
            accA = 0.f; accB = 0.f;
            #pragma unroll 4
            for (int kc = 0; kc < 16; ++kc) {
                uint4 wA = wcA[kc << 10], wB = wcB[kc << 10];
                uint4 h = h2u4[kc];
                accA = dot2(wA.x, h.x, accA); accA = dot2(wA.y, h.y, accA);
                accA = dot2(wA.z, h.z, accA); accA = dot2(wA.w, h.w, accA);
                accB = dot2(wB.x, h.x, accB); accB = dot2(wB.y, h.y, accB);
                accB = dot2(wB.z, h.z, accB); accB = dot2(wB.w, h.w, accB);
            }
        } else {
            const uint4* cat4 = dkh ? s2u4 : h2u4;
            float a = 0.f;
            #pragma unroll 8
            for (int i = 0; i < 32; ++i) {
                uint4 w = wwp[i << 8];
                uint4 c = cat4[i];
                a = dot2(w.x, c.x, a); a = dot2(w.y, c.y, a);
                a = dot2(w.z, c.z, a); a = dot2(w.w, c.w, a);
            }
            a += __shfl_xor(a, 1, 64);               // merge K-halves
            float ed = exp2f(1.442695041f * (a + bwm));   // e^{dsc}
            float ed2 = __shfl_xor(ed, 2, 64);            // partner m+1
            if ((aid & 3) == 0) {
                uint u = pk16(ed, ed2);
                edup[0][dm >> 1] = u;
                edup[1][dm >> 1] = u;
            }
        }
        __syncthreads();                             // Y: ED ready

        // ---- P3: G: acc kc 16..31 + write z   |   A: E_t (multiplicative tanh) ----
        if (wave < 8) {
            #pragma unroll 4
            for (int kc = 16; kc < 32; ++kc) {
                uint4 wA = wcA[kc << 10], wB = wcB[kc << 10];
                uint4 h = h2u4[kc];
                accA = dot2(wA.x, h.x, accA); accA = dot2(wA.y, h.y, accA);
                accA = dot2(wA.z, h.z, accA); accA = dot2(wA.w, h.w, accA);
                accB = dot2(wB.x, h.x, accB); accB = dot2(wB.y, h.y, accB);
                accB = dot2(wB.z, h.z, accB); accB = dot2(wB.w, h.w, accB);
            }
            z_lds[(tid >> 8) * 257 + (tid & 255)] = accA;
            z_lds[(2 + (tid >> 8)) * 257 + (tid & 255)] = accB;
        } else {
            __builtin_amdgcn_s_setprio(1);
            float pl = 0.f;                          // Σ 2wv / (e^{2x}+1)
            #pragma unroll 4
            for (int jj = 0; jj < 16; ++jj) {
                uint4 u = uecT[jj ^ ekey];
                uint4 d = edT[jj];
                float4 wA = wvT[jj * 2], wB = wvT[jj * 2 + 1];
                hf2 p0 = __builtin_bit_cast(hf2, u.x) * __builtin_bit_cast(hf2, d.x);
                hf2 p1 = __builtin_bit_cast(hf2, u.y) * __builtin_bit_cast(hf2, d.y);
                hf2 p2 = __builtin_bit_cast(hf2, u.z) * __builtin_bit_cast(hf2, d.z);
                hf2 p3 = __builtin_bit_cast(hf2, u.w) * __builtin_bit_cast(hf2, d.w);
                p0 = p0 * p0; p1 = p1 * p1; p2 = p2 * p2; p3 = p3 * p3;
                {
                    float a0 = fminf((float)p0.x, 1e18f) + 1.f;
                    float a1 = fminf((float)p0.y, 1e18f) + 1.f;
                    float qq = __builtin_amdgcn_rcpf(a0 * a1);
                    pl = fmaf(wA.x, a1 * qq, pl);
                    pl = fmaf(wA.y, a0 * qq, pl);
                }
                {
                    float a0 = fminf((float)p1.x, 1e18f) + 1.f;
                    float a1 = fminf((float)p1.y, 1e18f) + 1.f;
                    float qq = __builtin_amdgcn_rcpf(a0 * a1);
                    pl = fmaf(wA.z, a1 * qq, pl);
                    pl = fmaf(wA.w, a0 * qq, pl);
                }
                {
                    float a0 = fminf((float)p2.x, 1e18f) + 1.f;
                    float a1 = fminf((float)p2.y, 1e18f) + 1.f;
                    float qq = __builtin_amdgcn_rcpf(a0 * a1);
                    pl = fmaf(wB.x, a1 * qq, pl);
                    pl = fmaf(wB.y, a0 * qq, pl);
                }
                {
                    float a0 = fminf((float)p3.x, 1e18f) + 1.f;
                    float a1 = fminf((float)p3.y, 1e18f) + 1.f;
                    float qq = __builtin_amdgcn_rcpf(a0 * a1);
                    pl = fmaf(wB.z, a1 * qq, pl);
                    pl = fmaf(wB.w, a0 * qq, pl);
                }
            }
            pl += __shfl_xor(pl, 1, 64);             // merge m-halves
            // l = const - pl ; softmax-invariant constant dropped:
            float ev = exp2f(-1.442695041f * pl);
            if (!dkh) el_lds[dm] = ev;               // dm = row here
            float yg = ev * g_lds[dm];
            #pragma unroll
            for (int mm = 2; mm <= 32; mm <<= 1) {   // rows counted once (even lanes)
                ev += __shfl_xor(ev, mm, 64);
                yg += __shfl_xor(yg, mm, 64);
            }
            if (lane == 0) { sred[aw] = ev; yred[aw] = yg; }
            __builtin_amdgcn_s_setprio(0);
        }
        __syncthreads();                             // Z
    }

    // ---- epilogue: final ctx from el(254) + fp32 enc, then output head ----
    {
        float S;
        {
            float4 sa = *(const float4*)&sred[0], sb = *(const float4*)&sred[4];
            S = sa.x + sa.y + sa.z + sa.w + sb.x + sb.y + sb.z + sb.w;
        }
        float a0 = 0.f, a1 = 0.f, a2 = 0.f, a3 = 0.f;
        for (int i = 0; i < 16; ++i) {
            int tp = wave * 16 + i;
            float w = el_lds[tp];
            float4 e4 = *(const float4*)&encB[(size_t)tp * 256 + lane * 4];
            a0 += w * e4.x; a1 += w * e4.y; a2 += w * e4.z; a3 += w * e4.w;
        }
        atomicAdd(&ctx_lds[lane * 4 + 0], a0);
        atomicAdd(&ctx_lds[lane * 4 + 1], a1);
        atomicAdd(&ctx_lds[lane * 4 + 2], a2);
        atomicAdd(&ctx_lds[lane * 4 + 3], a3);
        __syncthreads();

        float qp = 0.f;
        if (tid < 256) {
            float ctx = ctx_lds[tid] * __builtin_amdgcn_rcpf(S);
            qp = h_lds[tid] * Wvb[tid] + ctx * Wvb[256 + tid];
        }
        if (wave < 4) {
            #pragma unroll
            for (int mm = 32; mm >= 1; mm >>= 1) qp += __shfl_xor(qp, mm, 64);
            if (lane == 0) ya[wave] = qp;
        }
        __syncthreads();
        if (tid < 256) {
            float qv = ya[0] + ya[1] + ya[2] + ya[3] + bvb[0];
            out[b * 256 + tid] = qv * Wwb[tid] + bwb[tid];
        }
    }
}

extern "C" void kernel_launch(void* const* d_in, const int* in_sizes, int n_in,
                              void* d_out, int out_size, void* d_ws, size_t ws_size,
                              hipStream_t stream) {
    const float* data = (const float*)d_in[0];
    const float* enc  = (const float*)d_in[1];
    const float* h0   = (const float*)d_in[2];
    const float* s0   = (const float*)d_in[3];
    const float* Wd   = (const float*)d_in[4];
    const float* bd   = (const float*)d_in[5];
    const float* Wk   = (const float*)d_in[6];
    const float* Wr   = (const float*)d_in[7];
    const float* bl   = (const float*)d_in[8];
    const float* Ww   = (const float*)d_in[9];
    const float* bw   = (const float*)d_in[10];
    const float* Wu   = (const float*)d_in[11];
    const float* bu   = (const float*)d_in[12];
    const float* Wv   = (const float*)d_in[13];
    const float* bv   = (const float*)d_in[14];
    const float* Wvb  = (const float*)d_in[15];
    const float* bvb  = (const float*)d_in[16];
    const float* Wwb  = (const float*)d_in[17];
    const float* bwb  = (const float*)d_in[18];

    _Float16* Ue16 = (_Float16*)d_ws;                                 // 32 MB
    uint4* Wsz  = (uint4*)((char*)d_ws + (32ull << 20));              // 512 KB
    uint4* Wwsz = (uint4*)((char*)d_ws + (32ull << 20) + (512ull << 10)); // 256 KB
    float* out = (float*)d_out;

    hipLaunchKernelGGL(ue_gemm, dim3((B * T) / 32), dim3(256), 0, stream,
                       enc, Wu, bu, Ue16);
    hipLaunchKernelGGL(wr_cvt, dim3(128), dim3(256), 0, stream, Wr, Wsz);
    hipLaunchKernelGGL(ww_cvt, dim3(64), dim3(256), 0, stream, Ww, Wwsz);
    hipLaunchKernelGGL(decoder_scan, dim3(B), dim3(NT), 0, stream,
                       data, h0, s0, Wd, bd, Wk, bl, bw,
                       Wv, bv, Wvb, bvb, Wwb, bwb,
                       enc, Ue16, Wsz, Wwsz, out);
}

// Round 8
// 2820.307 us; speedup vs baseline: 4.4215x; 1.0098x over previous
//
#include <hip/hip_runtime.h>
#include <hip/hip_bf16.h>

#define B 256
#define T 256
#define M 256
#define P 256
#define TSTEPS 255
#define NT 1024
#define RG 6      // G-resident Wr chunks per column
#define RA 8      // A-resident Ww chunks

typedef unsigned int uint;
typedef _Float16 hf2 __attribute__((ext_vector_type(2)));

__device__ __forceinline__ float fast_tanh(float x) {
    float e = exp2f(x * 2.885390082f);             // e^(2x)
    return 1.f - 2.f * __builtin_amdgcn_rcpf(e + 1.f);
}
__device__ __forceinline__ float fast_sigmoid(float x) {
    float e = exp2f(-x * 1.442695041f);            // e^(-x)
    return __builtin_amdgcn_rcpf(1.f + e);
}

#if defined(__has_builtin)
#if __has_builtin(__builtin_amdgcn_fdot2)
#define HAVE_FDOT2 1
#endif
#endif

__device__ __forceinline__ float dot2(uint a, uint b, float c) {
#ifdef HAVE_FDOT2
    return __builtin_amdgcn_fdot2(__builtin_bit_cast(hf2, a),
                                  __builtin_bit_cast(hf2, b), c, false);
#else
    hf2 x = __builtin_bit_cast(hf2, a), y = __builtin_bit_cast(hf2, b);
    return c + (float)x.x * (float)y.x + (float)x.y * (float)y.y;
#endif
}

__device__ __forceinline__ uint pk16(float a, float b) {
    return __builtin_bit_cast(uint, __builtin_amdgcn_cvt_pkrtz(a, b));
}

// ---------------- EU = f16(exp(encoder_h @ Wu + bu)) ----------------
__global__ __launch_bounds__(256) void ue_gemm(
    const float* __restrict__ enc, const float* __restrict__ Wu,
    const float* __restrict__ bu, _Float16* __restrict__ Ue16)
{
    __shared__ float At[32][256];
    const int r0 = blockIdx.x * 32;
    const int tid = threadIdx.x;

    #pragma unroll 4
    for (int i = 0; i < 32; ++i)
        At[i][tid] = enc[(size_t)(r0 + i) * 256 + tid];
    __syncthreads();

    float acc[32];
    #pragma unroll
    for (int r = 0; r < 32; ++r) acc[r] = 0.f;

    for (int k = 0; k < 256; k += 4) {
        float w0 = Wu[(size_t)(k + 0) * 256 + tid];
        float w1 = Wu[(size_t)(k + 1) * 256 + tid];
        float w2 = Wu[(size_t)(k + 2) * 256 + tid];
        float w3 = Wu[(size_t)(k + 3) * 256 + tid];
        #pragma unroll
        for (int r = 0; r < 32; ++r) {
            float4 a4 = *(const float4*)&At[r][k];
            acc[r] += a4.x * w0 + a4.y * w1 + a4.z * w2 + a4.w * w3;
        }
    }
    float bub = bu[tid];
    #pragma unroll 4
    for (int r = 0; r < 32; ++r)
        Ue16[(size_t)(r0 + r) * 256 + tid] =
            (_Float16)exp2f(1.442695041f * (acc[r] + bub));   // e^{u}
}

// ---- Wsz[kc*1024+c] = uint4 of f16 pairs of Wr[kc*8+j][c], j=0..7 ----
__global__ __launch_bounds__(256) void wr_cvt(
    const float* __restrict__ Wr, uint4* __restrict__ Wsz)
{
    int i = blockIdx.x * 256 + threadIdx.x;        // 32768
    int kc = i >> 10, c = i & 1023;
    const float* s = Wr + (size_t)kc * 8 * 1024 + c;
    uint4 o;
    o.x = pk16(s[0 * 1024], s[1 * 1024]);
    o.y = pk16(s[2 * 1024], s[3 * 1024]);
    o.z = pk16(s[4 * 1024], s[5 * 1024]);
    o.w = pk16(s[6 * 1024], s[7 * 1024]);
    Wsz[i] = o;
}

// ---- Wwsz[kk*256+m] = uint4 of f16 pairs of Ww[kk*8+j][m], j=0..7 ----
__global__ __launch_bounds__(256) void ww_cvt(
    const float* __restrict__ Ww, uint4* __restrict__ Wwsz)
{
    int i = blockIdx.x * 256 + threadIdx.x;        // 16384
    int kk = i >> 8, m = i & 255;
    const float* s = Ww + (size_t)kk * 8 * 256 + m;
    uint4 o;
    o.x = pk16(s[0 * 256], s[1 * 256]);
    o.y = pk16(s[2 * 256], s[3 * 256]);
    o.z = pk16(s[4 * 256], s[5 * 256]);
    o.w = pk16(s[6 * 256], s[7 * 256]);
    Wwsz[i] = o;
}

// ---------------- main scan: one block (1024 thr) per batch element ----------------
// Split loops: waves 0-7 (G) run {P1 gates; X; Wr stream; Z}. Waves 8-15 (A) run
// {prefetch; X; D; flag-sync; E; Z}. Barrier counts match (2/step each path).
__global__ __launch_bounds__(NT, 4) void decoder_scan(
    const float* __restrict__ data,
    const float* __restrict__ h0,  const float* __restrict__ s0,
    const float* __restrict__ Wd,  const float* __restrict__ bd,
    const float* __restrict__ Wk,  const float* __restrict__ bl,
    const float* __restrict__ bw,
    const float* __restrict__ Wv,  const float* __restrict__ bv,
    const float* __restrict__ Wvb, const float* __restrict__ bvb,
    const float* __restrict__ Wwb, const float* __restrict__ bwb,
    const float* __restrict__ enc,
    const _Float16* __restrict__ Ue16g,
    const uint4* __restrict__ Wsz, const uint4* __restrict__ Wwsz,
    float* __restrict__ out)
{
    const int b    = blockIdx.x;
    const int tid  = threadIdx.x;
    const int lane = tid & 63;
    const int wave = tid >> 6;          // 0..15

    __shared__ _Float16 ue_lds[T * M];          // 128 KB EU, chunk-swizzled
    __shared__ float h_lds[P], s_lds[P];
    __shared__ __align__(16) uint hs2[128 + 4 + 128];   // h2 @0, s2 @132
    __shared__ float z_lds[4 * 257];            // padded: row*257 + col
    __shared__ __align__(16) uint  edup[2][132];        // ED f16 pairs, dup copies
    __shared__ __align__(16) float wv2dup[2][264];      // 2*Wv f32, dup copies
    __shared__ float el_lds[T];
    __shared__ float g_lds[T];
    __shared__ float ctx_lds[M];
    __shared__ __align__(16) float sred[8], yred[8];
    __shared__ float ya[4];
    __shared__ float data_lds[TSTEPS + 1];
    __shared__ int aflag;

    uint* h2_lds = hs2;
    uint* s2_lds = hs2 + 132;

    // ---- stage EU into LDS, chunk-swizzled ----
    {
        const uint4* src = (const uint4*)(Ue16g + (size_t)b * T * M);
        uint4* dst = (uint4*)ue_lds;
        #pragma unroll
        for (int i = 0; i < 8; ++i) {
            int g = tid + i * NT;
            uint4 v = src[g];
            int r = g >> 5, lin = g & 31;
            int phys = (lin & 16) | ((lin ^ (2 * r + (lin >> 4))) & 15);
            dst[(r << 5) + phys] = v;
        }
    }
    if (tid == 0) aflag = 0;
    if (tid < 256) {
        float hv = h0[b * 256 + tid], sv = s0[b * 256 + tid];
        h_lds[tid] = hv; s_lds[tid] = sv; ctx_lds[tid] = 0.f;
        float w2 = 2.f * Wv[tid];
        wv2dup[0][tid] = w2; wv2dup[1][tid] = w2;
        float hv1 = __shfl_down(hv, 1, 64);
        float sv1 = __shfl_down(sv, 1, 64);
        if (!(tid & 1)) {
            h2_lds[tid >> 1] = pk16(hv, hv1);
            s2_lds[tid >> 1] = pk16(sv, sv1);
        }
    }
    if (tid < 8) { sred[tid] = 1.f; yred[tid] = 0.f; }   // ctx_0 = 0
    if (tid < TSTEPS) data_lds[tid] = data[b * TSTEPS + tid];

    const float Wd0 = Wd[0], bd0 = bd[0];
    const float* encB = enc + (size_t)b * T * M;

    // ---- g[tp] = <enc[tp,:], Wd[1:]> ----
    {
        float w0 = Wd[1 + lane * 4], w1 = Wd[2 + lane * 4];
        float w2 = Wd[3 + lane * 4], w3 = Wd[4 + lane * 4];
        for (int i = 0; i < 16; ++i) {
            int tp = wave * 16 + i;
            float4 e4 = *(const float4*)&encB[(size_t)tp * 256 + lane * 4];
            float p = e4.x * w0 + e4.y * w1 + e4.z * w2 + e4.w * w3;
            #pragma unroll
            for (int mm = 32; mm >= 1; mm >>= 1) p += __shfl_xor(p, mm, 64);
            if (lane == 0) g_lds[tp] = p;
        }
    }
    __syncthreads();

    const uint4* h2u4 = (const uint4*)h2_lds;
    const uint4* s2u4 = (const uint4*)s2_lds;

    // ---- prologue: acc_0 = Wr·h_0 (all threads, 1 col each) ----
    {
        const uint4* wc = Wsz + tid;
        float acc = 0.f;
        #pragma unroll 4
        for (int kc = 0; kc < 32; ++kc) {
            uint4 w = wc[kc << 10];
            uint4 h = h2u4[kc];
            acc = dot2(w.x, h.x, acc); acc = dot2(w.y, h.y, acc);
            acc = dot2(w.z, h.z, acc); acc = dot2(w.w, h.w, acc);
        }
        z_lds[(tid >> 8) * 257 + (tid & 255)] = acc;
    }
    __syncthreads();

    if (wave < 8) {
        // ================= G-path (512 threads) =================
        const int gate = tid & 3, uu0 = tid >> 2, uu1 = uu0 + 128;
        const int cz0 = gate * 257 + uu0, cz1 = gate * 257 + uu1;
        const float wk0 = Wk[gate * 256 + uu0], bl0 = bl[gate * 256 + uu0];
        const float wk1 = Wk[gate * 256 + uu1], bl1 = bl[gate * 256 + uu1];
        const int zr = tid >> 8, zc = tid & 255;
        const uint4* wcA = Wsz + tid;
        const uint4* wcB = Wsz + tid + 512;
        uint4 rA[RG], rB[RG];
        #pragma unroll
        for (int kc = 0; kc < RG; ++kc) { rA[kc] = wcA[kc << 10]; rB[kc] = wcB[kc << 10]; }

        for (int t = 0; t < TSTEPS; ++t) {
            // early-issue 4 streamed chunks (fly during P1)
            uint4 pA0 = wcA[(RG + 0) << 10], pB0 = wcB[(RG + 0) << 10];
            uint4 pA1 = wcA[(RG + 1) << 10], pB1 = wcB[(RG + 1) << 10];

            // ---- P1: ys; gates for 2 columns; write h,s,h2,s2 ----
            {
                float4 sa = *(const float4*)&sred[0], sb = *(const float4*)&sred[4];
                float4 yaa = *(const float4*)&yred[0], yab = *(const float4*)&yred[4];
                float S = sa.x + sa.y + sa.z + sa.w + sb.x + sb.y + sb.z + sb.w;
                float Y = yaa.x + yaa.y + yaa.z + yaa.w + yab.x + yab.y + yab.z + yab.w;
                float ys = Y * __builtin_amdgcn_rcpf(S) + data_lds[t] * Wd0 + bd0;
                float zc0 = z_lds[cz0] + ys * wk0 + bl0;
                float zc1 = z_lds[cz1] + ys * wk1 + bl1;
                float nl0 = (gate == 2) ? fast_tanh(zc0) : fast_sigmoid(zc0);
                float nl1 = (gate == 2) ? fast_tanh(zc1) : fast_sigmoid(zc1);
                float a1 = __shfl_xor(nl0, 1, 64);
                float a2 = __shfl_xor(nl0, 2, 64);
                float a3 = __shfl_xor(nl0, 3, 64);
                float b1 = __shfl_xor(nl1, 1, 64);
                float b2 = __shfl_xor(nl1, 2, 64);
                float b3 = __shfl_xor(nl1, 3, 64);
                float hn0 = 0.f, sv0 = 0.f, hn1 = 0.f, sv1 = 0.f;
                if (gate == 0) {            // nl=sig_i a1=sig_f a2=tanh_g a3=sig_o
                    sv0 = a1 * s_lds[uu0] + nl0 * a2;
                    hn0 = a3 * fast_tanh(sv0);
                    sv1 = b1 * s_lds[uu1] + nl1 * b2;
                    hn1 = b3 * fast_tanh(sv1);
                    s_lds[uu0] = sv0; h_lds[uu0] = hn0;
                    s_lds[uu1] = sv1; h_lds[uu1] = hn1;
                }
                float hd0 = __shfl_down(hn0, 4, 64), sd0 = __shfl_down(sv0, 4, 64);
                float hd1 = __shfl_down(hn1, 4, 64), sd1 = __shfl_down(sv1, 4, 64);
                if ((tid & 7) == 0) {
                    h2_lds[uu0 >> 1] = pk16(hn0, hd0); s2_lds[uu0 >> 1] = pk16(sv0, sd0);
                    h2_lds[uu1 >> 1] = pk16(hn1, hd1); s2_lds[uu1 >> 1] = pk16(sv1, sd1);
                }
            }
            __syncthreads();                         // X: h_{t+1} ready
            float a0 = 0.f, a1 = 0.f;
            #pragma unroll
            for (int kc = 0; kc < RG; ++kc) {        // resident: pure VALU
                uint4 h = h2u4[kc];
                a0 = dot2(rA[kc].x, h.x, a0); a0 = dot2(rA[kc].y, h.y, a0);
                a0 = dot2(rA[kc].z, h.z, a0); a0 = dot2(rA[kc].w, h.w, a0);
                a1 = dot2(rB[kc].x, h.x, a1); a1 = dot2(rB[kc].y, h.y, a1);
                a1 = dot2(rB[kc].z, h.z, a1); a1 = dot2(rB[kc].w, h.w, a1);
            }
            {
                uint4 h = h2u4[RG];
                a0 = dot2(pA0.x, h.x, a0); a0 = dot2(pA0.y, h.y, a0);
                a0 = dot2(pA0.z, h.z, a0); a0 = dot2(pA0.w, h.w, a0);
                a1 = dot2(pB0.x, h.x, a1); a1 = dot2(pB0.y, h.y, a1);
                a1 = dot2(pB0.z, h.z, a1); a1 = dot2(pB0.w, h.w, a1);
            }
            {
                uint4 h = h2u4[RG + 1];
                a0 = dot2(pA1.x, h.x, a0); a0 = dot2(pA1.y, h.y, a0);
                a0 = dot2(pA1.z, h.z, a0); a0 = dot2(pA1.w, h.w, a0);
                a1 = dot2(pB1.x, h.x, a1); a1 = dot2(pB1.y, h.y, a1);
                a1 = dot2(pB1.z, h.z, a1); a1 = dot2(pB1.w, h.w, a1);
            }
            #pragma unroll 4
            for (int kc = RG + 2; kc < 32; ++kc) {   // streamed
                uint4 wA = wcA[kc << 10], wB = wcB[kc << 10];
                uint4 h = h2u4[kc];
                a0 = dot2(wA.x, h.x, a0); a0 = dot2(wA.y, h.y, a0);
                a0 = dot2(wA.z, h.z, a0); a0 = dot2(wA.w, h.w, a0);
                a1 = dot2(wB.x, h.x, a1); a1 = dot2(wB.y, h.y, a1);
                a1 = dot2(wB.z, h.z, a1); a1 = dot2(wB.w, h.w, a1);
            }
            z_lds[zr * 257 + zc] = a0;
            z_lds[(2 + zr) * 257 + zc] = a1;
            __syncthreads();                         // Z
        }
    } else {
        // ================= A-path (512 threads) =================
        const int aw  = wave - 8;
        const int aid = tid - 512;
        const int dm  = aid >> 1;                   // D: m-col / E: row
        const int dkh = aid & 1;                    // D: K-half, E: m-half
        const int ekey = aid & 15;
        const float bwm = bw[dm];
        const uint4* wwp  = Wwsz + (dkh << 13) + dm;
        const uint4* uecT = (const uint4*)ue_lds + (aid << 4);
        const uint4*  edT = (const uint4*)(&edup[dkh][0]) + (dkh << 4);
        const float4* wvT = (const float4*)(&wv2dup[dkh][0]) + (dkh << 5);
        const uint4* cat4 = dkh ? s2u4 : h2u4;
        uint4 rW[RA];
        #pragma unroll
        for (int i = 0; i < RA; ++i) rW[i] = wwp[i << 8];

        for (int t = 0; t < TSTEPS; ++t) {
            // early-issue 4 streamed Ww chunks (fly during G's P1)
            uint4 e0 = wwp[(RA + 0) << 8], e1 = wwp[(RA + 1) << 8];
            uint4 e2 = wwp[(RA + 2) << 8], e3 = wwp[(RA + 3) << 8];
            __syncthreads();                         // X: h2/s2 ready
            // ---- D: dsc column dm, K-half dkh ----
            float a = 0.f;
            #pragma unroll
            for (int i = 0; i < RA; ++i) {
                uint4 c = cat4[i];
                a = dot2(rW[i].x, c.x, a); a = dot2(rW[i].y, c.y, a);
                a = dot2(rW[i].z, c.z, a); a = dot2(rW[i].w, c.w, a);
            }
            {
                uint4 c = cat4[RA + 0];
                a = dot2(e0.x, c.x, a); a = dot2(e0.y, c.y, a);
                a = dot2(e0.z, c.z, a); a = dot2(e0.w, c.w, a);
                c = cat4[RA + 1];
                a = dot2(e1.x, c.x, a); a = dot2(e1.y, c.y, a);
                a = dot2(e1.z, c.z, a); a = dot2(e1.w, c.w, a);
                c = cat4[RA + 2];
                a = dot2(e2.x, c.x, a); a = dot2(e2.y, c.y, a);
                a = dot2(e2.z, c.z, a); a = dot2(e2.w, c.w, a);
                c = cat4[RA + 3];
                a = dot2(e3.x, c.x, a); a = dot2(e3.y, c.y, a);
                a = dot2(e3.z, c.z, a); a = dot2(e3.w, c.w, a);
            }
            #pragma unroll 4
            for (int i = RA + 4; i < 32; ++i) {
                uint4 w = wwp[i << 8];
                uint4 c = cat4[i];
                a = dot2(w.x, c.x, a); a = dot2(w.y, c.y, a);
                a = dot2(w.z, c.z, a); a = dot2(w.w, c.w, a);
            }
            a += __shfl_xor(a, 1, 64);               // merge K-halves
            float ed = exp2f(1.442695041f * (a + bwm));   // e^{dsc}
            float ed2 = __shfl_xor(ed, 2, 64);            // partner m+1
            if ((aid & 3) == 0) {
                uint u = pk16(ed, ed2);
                edup[0][dm >> 1] = u;
                edup[1][dm >> 1] = u;
            }
            // ---- A-internal sync: all ED written ----
            __threadfence_block();
            if (lane == 0) atomicAdd(&aflag, 1);
            const int tgt = 8 * (t + 1);
            while (*(volatile int*)&aflag < tgt) {}
            __threadfence_block();

            // ---- E: multiplicative tanh, row dm, m-half dkh ----
            __builtin_amdgcn_s_setprio(1);
            float pl = 0.f;                          // Σ 2wv / (e^{2x}+1)
            #pragma unroll 4
            for (int jj = 0; jj < 16; ++jj) {
                uint4 u = uecT[jj ^ ekey];
                uint4 d = edT[jj];
                float4 wA = wvT[jj * 2], wB = wvT[jj * 2 + 1];
                hf2 p0 = __builtin_bit_cast(hf2, u.x) * __builtin_bit_cast(hf2, d.x);
                hf2 p1 = __builtin_bit_cast(hf2, u.y) * __builtin_bit_cast(hf2, d.y);
                hf2 p2 = __builtin_bit_cast(hf2, u.z) * __builtin_bit_cast(hf2, d.z);
                hf2 p3 = __builtin_bit_cast(hf2, u.w) * __builtin_bit_cast(hf2, d.w);
                p0 = p0 * p0; p1 = p1 * p1; p2 = p2 * p2; p3 = p3 * p3;
                {
                    float a0 = fminf((float)p0.x, 1e18f) + 1.f;
                    float a1 = fminf((float)p0.y, 1e18f) + 1.f;
                    float qq = __builtin_amdgcn_rcpf(a0 * a1);
                    pl = fmaf(wA.x, a1 * qq, pl);
                    pl = fmaf(wA.y, a0 * qq, pl);
                }
                {
                    float a0 = fminf((float)p1.x, 1e18f) + 1.f;
                    float a1 = fminf((float)p1.y, 1e18f) + 1.f;
                    float qq = __builtin_amdgcn_rcpf(a0 * a1);
                    pl = fmaf(wA.z, a1 * qq, pl);
                    pl = fmaf(wA.w, a0 * qq, pl);
                }
                {
                    float a0 = fminf((float)p2.x, 1e18f) + 1.f;
                    float a1 = fminf((float)p2.y, 1e18f) + 1.f;
                    float qq = __builtin_amdgcn_rcpf(a0 * a1);
                    pl = fmaf(wB.x, a1 * qq, pl);
                    pl = fmaf(wB.y, a0 * qq, pl);
                }
                {
                    float a0 = fminf((float)p3.x, 1e18f) + 1.f;
                    float a1 = fminf((float)p3.y, 1e18f) + 1.f;
                    float qq = __builtin_amdgcn_rcpf(a0 * a1);
                    pl = fmaf(wB.z, a1 * qq, pl);
                    pl = fmaf(wB.w, a0 * qq, pl);
                }
            }
            pl += __shfl_xor(pl, 1, 64);             // merge m-halves
            float ev = exp2f(-1.442695041f * pl);    // softmax const dropped
            if (!dkh) el_lds[dm] = ev;
            float yg = ev * g_lds[dm];
            #pragma unroll
            for (int mm = 2; mm <= 32; mm <<= 1) {
                ev += __shfl_xor(ev, mm, 64);
                yg += __shfl_xor(yg, mm, 64);
            }
            if (lane == 0) { sred[aw] = ev; yred[aw] = yg; }
            __builtin_amdgcn_s_setprio(0);
            __syncthreads();                         // Z
        }
    }

    // ---- epilogue: final ctx from el(254) + fp32 enc, then output head ----
    {
        float S;
        {
            float4 sa = *(const float4*)&sred[0], sb = *(const float4*)&sred[4];
            S = sa.x + sa.y + sa.z + sa.w + sb.x + sb.y + sb.z + sb.w;
        }
        float a0 = 0.f, a1 = 0.f, a2 = 0.f, a3 = 0.f;
        for (int i = 0; i < 16; ++i) {
            int tp = wave * 16 + i;
            float w = el_lds[tp];
            float4 e4 = *(const float4*)&encB[(size_t)tp * 256 + lane * 4];
            a0 += w * e4.x; a1 += w * e4.y; a2 += w * e4.z; a3 += w * e4.w;
        }
        atomicAdd(&ctx_lds[lane * 4 + 0], a0);
        atomicAdd(&ctx_lds[lane * 4 + 1], a1);
        atomicAdd(&ctx_lds[lane * 4 + 2], a2);
        atomicAdd(&ctx_lds[lane * 4 + 3], a3);
        __syncthreads();

        float qp = 0.f;
        if (tid < 256) {
            float ctx = ctx_lds[tid] * __builtin_amdgcn_rcpf(S);
            qp = h_lds[tid] * Wvb[tid] + ctx * Wvb[256 + tid];
        }
        if (wave < 4) {
            #pragma unroll
            for (int mm = 32; mm >= 1; mm >>= 1) qp += __shfl_xor(qp, mm, 64);
            if (lane == 0) ya[wave] = qp;
        }
        __syncthreads();
        if (tid < 256) {
            float qv = ya[0] + ya[1] + ya[2] + ya[3] + bvb[0];
            out[b * 256 + tid] = qv * Wwb[tid] + bwb[tid];
        }
    }
}

extern "C" void kernel_launch(void* const* d_in, const int* in_sizes, int n_in,
                              void* d_out, int out_size, void* d_ws, size_t ws_size,
                              hipStream_t stream) {
    const float* data = (const float*)d_in[0];
    const float* enc  = (const float*)d_in[1];
    const float* h0   = (const float*)d_in[2];
    const float* s0   = (const float*)d_in[3];
    const float* Wd   = (const float*)d_in[4];
    const float* bd   = (const float*)d_in[5];
    const float* Wk   = (const float*)d_in[6];
    const float* Wr   = (const float*)d_in[7];
    const float* bl   = (const float*)d_in[8];
    const float* Ww   = (const float*)d_in[9];
    const float* bw   = (const float*)d_in[10];
    const float* Wu   = (const float*)d_in[11];
    const float* bu   = (const float*)d_in[12];
    const float* Wv   = (const float*)d_in[13];
    const float* bv   = (const float*)d_in[14];
    const float* Wvb  = (const float*)d_in[15];
    const float* bvb  = (const float*)d_in[16];
    const float* Wwb  = (const float*)d_in[17];
    const float* bwb  = (const float*)d_in[18];

    _Float16* Ue16 = (_Float16*)d_ws;                                 // 32 MB
    uint4* Wsz  = (uint4*)((char*)d_ws + (32ull << 20));              // 512 KB
    uint4* Wwsz = (uint4*)((char*)d_ws + (32ull << 20) + (512ull << 10)); // 256 KB
    float* out = (float*)d_out;

    hipLaunchKernelGGL(ue_gemm, dim3((B * T) / 32), dim3(256), 0, stream,
                       enc, Wu, bu, Ue16);
    hipLaunchKernelGGL(wr_cvt, dim3(128), dim3(256), 0, stream, Wr, Wsz);
    hipLaunchKernelGGL(ww_cvt, dim3(64), dim3(256), 0, stream, Ww, Wwsz);
    hipLaunchKernelGGL(decoder_scan, dim3(B), dim3(NT), 0, stream,
                       data, h0, s0, Wd, bd, Wk, bl, bw,
                       Wv, bv, Wvb, bvb, Wwb, bwb,
                       enc, Ue16, Wsz, Wwsz, out);
}

// Round 9
// 2644.062 us; speedup vs baseline: 4.7162x; 1.0667x over previous
//
#include <hip/hip_runtime.h>
#include <hip/hip_bf16.h>

#define B 256
#define T 256
#define M 256
#define P 256
#define TSTEPS 255
#define NT 1024
#define RG 6      // G-resident Wr chunk-pairs (asm-pinned)

typedef unsigned int uint;
typedef _Float16 hf2 __attribute__((ext_vector_type(2)));

#define KEEP4(v) asm volatile("" : "+v"((v).x), "+v"((v).y), "+v"((v).z), "+v"((v).w))

__device__ __forceinline__ float fast_tanh(float x) {
    float e = exp2f(x * 2.885390082f);             // e^(2x)
    return 1.f - 2.f * __builtin_amdgcn_rcpf(e + 1.f);
}
__device__ __forceinline__ float fast_sigmoid(float x) {
    float e = exp2f(-x * 1.442695041f);            // e^(-x)
    return __builtin_amdgcn_rcpf(1.f + e);
}

#if defined(__has_builtin)
#if __has_builtin(__builtin_amdgcn_fdot2)
#define HAVE_FDOT2 1
#endif
#endif

__device__ __forceinline__ float dot2(uint a, uint b, float c) {
#ifdef HAVE_FDOT2
    return __builtin_amdgcn_fdot2(__builtin_bit_cast(hf2, a),
                                  __builtin_bit_cast(hf2, b), c, false);
#else
    hf2 x = __builtin_bit_cast(hf2, a), y = __builtin_bit_cast(hf2, b);
    return c + (float)x.x * (float)y.x + (float)x.y * (float)y.y;
#endif
}

__device__ __forceinline__ uint pk16(float a, float b) {
    return __builtin_bit_cast(uint, __builtin_amdgcn_cvt_pkrtz(a, b));
}

// ---------------- EU = f16(exp(encoder_h @ Wu + bu)) ----------------
__global__ __launch_bounds__(256) void ue_gemm(
    const float* __restrict__ enc, const float* __restrict__ Wu,
    const float* __restrict__ bu, _Float16* __restrict__ Ue16)
{
    __shared__ float At[32][256];
    const int r0 = blockIdx.x * 32;
    const int tid = threadIdx.x;

    #pragma unroll 4
    for (int i = 0; i < 32; ++i)
        At[i][tid] = enc[(size_t)(r0 + i) * 256 + tid];
    __syncthreads();

    float acc[32];
    #pragma unroll
    for (int r = 0; r < 32; ++r) acc[r] = 0.f;

    for (int k = 0; k < 256; k += 4) {
        float w0 = Wu[(size_t)(k + 0) * 256 + tid];
        float w1 = Wu[(size_t)(k + 1) * 256 + tid];
        float w2 = Wu[(size_t)(k + 2) * 256 + tid];
        float w3 = Wu[(size_t)(k + 3) * 256 + tid];
        #pragma unroll
        for (int r = 0; r < 32; ++r) {
            float4 a4 = *(const float4*)&At[r][k];
            acc[r] += a4.x * w0 + a4.y * w1 + a4.z * w2 + a4.w * w3;
        }
    }
    float bub = bu[tid];
    #pragma unroll 4
    for (int r = 0; r < 32; ++r)
        Ue16[(size_t)(r0 + r) * 256 + tid] =
            (_Float16)exp2f(1.442695041f * (acc[r] + bub));   // e^{u}
}

// ---- Wsz[kc*1024+c] = uint4 of f16 pairs of Wr[kc*8+j][c], j=0..7 ----
__global__ __launch_bounds__(256) void wr_cvt(
    const float* __restrict__ Wr, uint4* __restrict__ Wsz)
{
    int i = blockIdx.x * 256 + threadIdx.x;        // 32768
    int kc = i >> 10, c = i & 1023;
    const float* s = Wr + (size_t)kc * 8 * 1024 + c;
    uint4 o;
    o.x = pk16(s[0 * 1024], s[1 * 1024]);
    o.y = pk16(s[2 * 1024], s[3 * 1024]);
    o.z = pk16(s[4 * 1024], s[5 * 1024]);
    o.w = pk16(s[6 * 1024], s[7 * 1024]);
    Wsz[i] = o;
}

// ---- Wwsz[kk*256+m] = uint4 of f16 pairs of Ww[kk*8+j][m], j=0..7 ----
__global__ __launch_bounds__(256) void ww_cvt(
    const float* __restrict__ Ww, uint4* __restrict__ Wwsz)
{
    int i = blockIdx.x * 256 + threadIdx.x;        // 16384
    int kk = i >> 8, m = i & 255;
    const float* s = Ww + (size_t)kk * 8 * 256 + m;
    uint4 o;
    o.x = pk16(s[0 * 256], s[1 * 256]);
    o.y = pk16(s[2 * 256], s[3 * 256]);
    o.z = pk16(s[4 * 256], s[5 * 256]);
    o.w = pk16(s[6 * 256], s[7 * 256]);
    Wwsz[i] = o;
}

// ---------------- main scan: one block (1024 thr) per batch element ----------------
// G-waves 0-7: {P1 gates; X; Wr matvec (RG reg-resident + stream); Z}
// A-waves 8-15: {X; D (16 LDS + 16 stream chunks); flag; E (EU in regs); Z}
__global__ __launch_bounds__(NT, 4) void decoder_scan(
    const float* __restrict__ data,
    const float* __restrict__ h0,  const float* __restrict__ s0,
    const float* __restrict__ Wd,  const float* __restrict__ bd,
    const float* __restrict__ Wk,  const float* __restrict__ bl,
    const float* __restrict__ bw,
    const float* __restrict__ Wv,  const float* __restrict__ bv,
    const float* __restrict__ Wvb, const float* __restrict__ bvb,
    const float* __restrict__ Wwb, const float* __restrict__ bwb,
    const float* __restrict__ enc,
    const _Float16* __restrict__ Ue16g,
    const uint4* __restrict__ Wsz, const uint4* __restrict__ Wwsz,
    float* __restrict__ out)
{
    const int b    = blockIdx.x;
    const int tid  = threadIdx.x;
    const int lane = tid & 63;
    const int wave = tid >> 6;          // 0..15

    __shared__ __align__(16) uint4 ww_lds[2 * 16 * 256];   // 128 KB: kk {0..15}∪{32..47}
    __shared__ float h_lds[P], s_lds[P];
    __shared__ __align__(16) uint hs2[128 + 4 + 128];      // h2 @0, s2 @132
    __shared__ float z_lds[4 * 257];
    __shared__ __align__(16) uint  edup[2][132];           // ED f16 pairs, dup copies
    __shared__ __align__(16) float wv2dup[2][264];         // 2*Wv f32, dup copies
    __shared__ float el_lds[T];
    __shared__ float g_lds[T];
    __shared__ float ctx_lds[M];
    __shared__ __align__(16) float sred[8], yred[8];
    __shared__ float ya[4];
    __shared__ float data_lds[TSTEPS + 1];
    __shared__ int aflag;

    uint* h2_lds = hs2;
    uint* s2_lds = hs2 + 132;

    // ---- stage Ww halves into LDS: dst[(dkh*16+i)*256+m] = Wwsz[(dkh*32+i)*256+m]
    {
        #pragma unroll
        for (int k = 0; k < 8; ++k) {
            int l = tid + k * NT;                  // 0..8191
            int m = l & 255, i = (l >> 8) & 15, dk = l >> 12;
            ww_lds[l] = Wwsz[((dk * 32 + i) << 8) + m];
        }
    }
    if (tid == 0) aflag = 0;
    if (tid < 256) {
        float hv = h0[b * 256 + tid], sv = s0[b * 256 + tid];
        h_lds[tid] = hv; s_lds[tid] = sv; ctx_lds[tid] = 0.f;
        float w2 = 2.f * Wv[tid];
        wv2dup[0][tid] = w2; wv2dup[1][tid] = w2;
        float hv1 = __shfl_down(hv, 1, 64);
        float sv1 = __shfl_down(sv, 1, 64);
        if (!(tid & 1)) {
            h2_lds[tid >> 1] = pk16(hv, hv1);
            s2_lds[tid >> 1] = pk16(sv, sv1);
        }
    }
    if (tid < 8) { sred[tid] = 1.f; yred[tid] = 0.f; }   // ctx_0 = 0
    if (tid < TSTEPS) data_lds[tid] = data[b * TSTEPS + tid];

    const float Wd0 = Wd[0], bd0 = bd[0];
    const float* encB = enc + (size_t)b * T * M;

    // ---- g[tp] = <enc[tp,:], Wd[1:]> ----
    {
        float w0 = Wd[1 + lane * 4], w1 = Wd[2 + lane * 4];
        float w2 = Wd[3 + lane * 4], w3 = Wd[4 + lane * 4];
        for (int i = 0; i < 16; ++i) {
            int tp = wave * 16 + i;
            float4 e4 = *(const float4*)&encB[(size_t)tp * 256 + lane * 4];
            float p = e4.x * w0 + e4.y * w1 + e4.z * w2 + e4.w * w3;
            #pragma unroll
            for (int mm = 32; mm >= 1; mm >>= 1) p += __shfl_xor(p, mm, 64);
            if (lane == 0) g_lds[tp] = p;
        }
    }
    __syncthreads();

    const uint4* h2u4 = (const uint4*)h2_lds;
    const uint4* s2u4 = (const uint4*)s2_lds;

    // ---- prologue: acc_0 = Wr·h_0 (all threads, 1 col each) ----
    {
        const uint4* wc = Wsz + tid;
        float acc = 0.f;
        #pragma unroll 4
        for (int kc = 0; kc < 32; ++kc) {
            uint4 w = wc[kc << 10];
            uint4 h = h2u4[kc];
            acc = dot2(w.x, h.x, acc); acc = dot2(w.y, h.y, acc);
            acc = dot2(w.z, h.z, acc); acc = dot2(w.w, h.w, acc);
        }
        z_lds[(tid >> 8) * 257 + (tid & 255)] = acc;
    }
    __syncthreads();

    if (wave < 8) {
        // ================= G-path (512 threads) =================
        const int gate = tid & 3, uu0 = tid >> 2, uu1 = uu0 + 128;
        const int cz0 = gate * 257 + uu0, cz1 = gate * 257 + uu1;
        const float wk0 = Wk[gate * 256 + uu0], bl0 = bl[gate * 256 + uu0];
        const float wk1 = Wk[gate * 256 + uu1], bl1 = bl[gate * 256 + uu1];
        const int zr = tid >> 8, zc = tid & 255;
        const uint4* wcA = Wsz + tid;
        const uint4* wcB = Wsz + tid + 512;
        uint4 rA[RG], rB[RG];
        #pragma unroll
        for (int kc = 0; kc < RG; ++kc) {
            rA[kc] = wcA[kc << 10]; rB[kc] = wcB[kc << 10];
            KEEP4(rA[kc]); KEEP4(rB[kc]);
        }

        for (int t = 0; t < TSTEPS; ++t) {
            // ---- P1: ys; gates for 2 columns; write h,s,h2,s2 ----
            {
                float4 sa = *(const float4*)&sred[0], sb = *(const float4*)&sred[4];
                float4 yaa = *(const float4*)&yred[0], yab = *(const float4*)&yred[4];
                float S = sa.x + sa.y + sa.z + sa.w + sb.x + sb.y + sb.z + sb.w;
                float Y = yaa.x + yaa.y + yaa.z + yaa.w + yab.x + yab.y + yab.z + yab.w;
                float ys = Y * __builtin_amdgcn_rcpf(S) + data_lds[t] * Wd0 + bd0;
                float zc0 = z_lds[cz0] + ys * wk0 + bl0;
                float zc1 = z_lds[cz1] + ys * wk1 + bl1;
                float nl0 = (gate == 2) ? fast_tanh(zc0) : fast_sigmoid(zc0);
                float nl1 = (gate == 2) ? fast_tanh(zc1) : fast_sigmoid(zc1);
                float a1 = __shfl_xor(nl0, 1, 64);
                float a2 = __shfl_xor(nl0, 2, 64);
                float a3 = __shfl_xor(nl0, 3, 64);
                float b1 = __shfl_xor(nl1, 1, 64);
                float b2 = __shfl_xor(nl1, 2, 64);
                float b3 = __shfl_xor(nl1, 3, 64);
                float hn0 = 0.f, sv0 = 0.f, hn1 = 0.f, sv1 = 0.f;
                if (gate == 0) {            // nl=sig_i a1=sig_f a2=tanh_g a3=sig_o
                    sv0 = a1 * s_lds[uu0] + nl0 * a2;
                    hn0 = a3 * fast_tanh(sv0);
                    sv1 = b1 * s_lds[uu1] + nl1 * b2;
                    hn1 = b3 * fast_tanh(sv1);
                    s_lds[uu0] = sv0; h_lds[uu0] = hn0;
                    s_lds[uu1] = sv1; h_lds[uu1] = hn1;
                }
                float hd0 = __shfl_down(hn0, 4, 64), sd0 = __shfl_down(sv0, 4, 64);
                float hd1 = __shfl_down(hn1, 4, 64), sd1 = __shfl_down(sv1, 4, 64);
                if ((tid & 7) == 0) {
                    h2_lds[uu0 >> 1] = pk16(hn0, hd0); s2_lds[uu0 >> 1] = pk16(sv0, sd0);
                    h2_lds[uu1 >> 1] = pk16(hn1, hd1); s2_lds[uu1 >> 1] = pk16(sv1, sd1);
                }
            }
            __syncthreads();                         // X: h_{t+1} ready

            float a0 = 0.f, a1 = 0.f;
            #pragma unroll
            for (int kc = 0; kc < RG; ++kc) {        // reg-resident: pure VALU
                uint4 h = h2u4[kc];
                a0 = dot2(rA[kc].x, h.x, a0); a0 = dot2(rA[kc].y, h.y, a0);
                a0 = dot2(rA[kc].z, h.z, a0); a0 = dot2(rA[kc].w, h.w, a0);
                a1 = dot2(rB[kc].x, h.x, a1); a1 = dot2(rB[kc].y, h.y, a1);
                a1 = dot2(rB[kc].z, h.z, a1); a1 = dot2(rB[kc].w, h.w, a1);
            }
            #pragma unroll 4
            for (int kc = RG; kc < 32; ++kc) {       // streamed from L2
                uint4 wA = wcA[kc << 10], wB = wcB[kc << 10];
                uint4 h = h2u4[kc];
                a0 = dot2(wA.x, h.x, a0); a0 = dot2(wA.y, h.y, a0);
                a0 = dot2(wA.z, h.z, a0); a0 = dot2(wA.w, h.w, a0);
                a1 = dot2(wB.x, h.x, a1); a1 = dot2(wB.y, h.y, a1);
                a1 = dot2(wB.z, h.z, a1); a1 = dot2(wB.w, h.w, a1);
            }
            z_lds[zr * 257 + zc] = a0;
            z_lds[(2 + zr) * 257 + zc] = a1;
            __syncthreads();                         // Z
        }
    } else {
        // ================= A-path (512 threads) =================
        const int aw  = wave - 8;
        const int aid = tid - 512;
        const int dm  = aid >> 1;                   // D: m-col / E: row
        const int dkh = aid & 1;                    // D: K-half, E: m-half
        const float bwm = bw[dm];
        const uint4* wwp  = Wwsz + (dkh << 13) + dm;        // global, kk=dkh*32+i
        const uint4* wwl  = ww_lds + (dkh << 12) + dm;      // LDS, i=0..15
        const uint4*  edT = (const uint4*)(&edup[dkh][0]) + (dkh << 4);
        const float4* wvT = (const float4*)(&wv2dup[dkh][0]) + (dkh << 5);
        const uint4* cat4 = dkh ? s2u4 : h2u4;

        // ---- EU row-half into registers (64 VGPR, pinned) ----
        uint4 eu[16];
        {
            const uint4* eusrc = (const uint4*)(Ue16g + (size_t)b * T * M) + (aid << 4);
            #pragma unroll
            for (int i = 0; i < 16; ++i) { eu[i] = eusrc[i]; KEEP4(eu[i]); }
        }

        for (int t = 0; t < TSTEPS; ++t) {
            __syncthreads();                         // X: h2/s2 ready
            // ---- D: dsc column dm, K-half dkh: 16 LDS chunks + 16 streamed ----
            float a = 0.f;
            #pragma unroll 4
            for (int i = 0; i < 16; ++i) {
                uint4 w = wwl[i << 8];
                uint4 c = cat4[i];
                a = dot2(w.x, c.x, a); a = dot2(w.y, c.y, a);
                a = dot2(w.z, c.z, a); a = dot2(w.w, c.w, a);
            }
            #pragma unroll 4
            for (int i = 16; i < 32; ++i) {
                uint4 w = wwp[i << 8];
                uint4 c = cat4[i];
                a = dot2(w.x, c.x, a); a = dot2(w.y, c.y, a);
                a = dot2(w.z, c.z, a); a = dot2(w.w, c.w, a);
            }
            a += __shfl_xor(a, 1, 64);               // merge K-halves
            float ed = exp2f(1.442695041f * (a + bwm));   // e^{dsc}
            float ed2 = __shfl_xor(ed, 2, 64);            // partner m+1
            if ((aid & 3) == 0) {
                uint u = pk16(ed, ed2);
                edup[0][dm >> 1] = u;
                edup[1][dm >> 1] = u;
            }
            // ---- A-internal sync: all ED written ----
            __threadfence_block();
            if (lane == 0) atomicAdd(&aflag, 1);
            const int tgt = 8 * (t + 1);
            while (*(volatile int*)&aflag < tgt) __builtin_amdgcn_s_sleep(1);
            __threadfence_block();

            // ---- E: multiplicative tanh, row dm, m-half dkh (EU in regs) ----
            __builtin_amdgcn_s_setprio(1);
            float pl = 0.f;                          // Σ 2wv / (e^{2x}+1)
            #pragma unroll
            for (int jj = 0; jj < 16; ++jj) {
                uint4 u = eu[jj];
                uint4 d = edT[jj];
                float4 wA = wvT[jj * 2], wB = wvT[jj * 2 + 1];
                hf2 p0 = __builtin_bit_cast(hf2, u.x) * __builtin_bit_cast(hf2, d.x);
                hf2 p1 = __builtin_bit_cast(hf2, u.y) * __builtin_bit_cast(hf2, d.y);
                hf2 p2 = __builtin_bit_cast(hf2, u.z) * __builtin_bit_cast(hf2, d.z);
                hf2 p3 = __builtin_bit_cast(hf2, u.w) * __builtin_bit_cast(hf2, d.w);
                p0 = p0 * p0; p1 = p1 * p1; p2 = p2 * p2; p3 = p3 * p3;
                {
                    float a0 = fminf((float)p0.x, 1e18f) + 1.f;
                    float a1 = fminf((float)p0.y, 1e18f) + 1.f;
                    float qq = __builtin_amdgcn_rcpf(a0 * a1);
                    pl = fmaf(wA.x, a1 * qq, pl);
                    pl = fmaf(wA.y, a0 * qq, pl);
                }
                {
                    float a0 = fminf((float)p1.x, 1e18f) + 1.f;
                    float a1 = fminf((float)p1.y, 1e18f) + 1.f;
                    float qq = __builtin_amdgcn_rcpf(a0 * a1);
                    pl = fmaf(wA.z, a1 * qq, pl);
                    pl = fmaf(wA.w, a0 * qq, pl);
                }
                {
                    float a0 = fminf((float)p2.x, 1e18f) + 1.f;
                    float a1 = fminf((float)p2.y, 1e18f) + 1.f;
                    float qq = __builtin_amdgcn_rcpf(a0 * a1);
                    pl = fmaf(wB.x, a1 * qq, pl);
                    pl = fmaf(wB.y, a0 * qq, pl);
                }
                {
                    float a0 = fminf((float)p3.x, 1e18f) + 1.f;
                    float a1 = fminf((float)p3.y, 1e18f) + 1.f;
                    float qq = __builtin_amdgcn_rcpf(a0 * a1);
                    pl = fmaf(wB.z, a1 * qq, pl);
                    pl = fmaf(wB.w, a0 * qq, pl);
                }
            }
            pl += __shfl_xor(pl, 1, 64);             // merge m-halves
            float ev = exp2f(-1.442695041f * pl);    // softmax const dropped
            if (!dkh) el_lds[dm] = ev;
            float yg = ev * g_lds[dm];
            #pragma unroll
            for (int mm = 2; mm <= 32; mm <<= 1) {
                ev += __shfl_xor(ev, mm, 64);
                yg += __shfl_xor(yg, mm, 64);
            }
            if (lane == 0) { sred[aw] = ev; yred[aw] = yg; }
            __builtin_amdgcn_s_setprio(0);
            __syncthreads();                         // Z
        }
    }

    // ---- epilogue: final ctx from el(254) + fp32 enc, then output head ----
    {
        float S;
        {
            float4 sa = *(const float4*)&sred[0], sb = *(const float4*)&sred[4];
            S = sa.x + sa.y + sa.z + sa.w + sb.x + sb.y + sb.z + sb.w;
        }
        float a0 = 0.f, a1 = 0.f, a2 = 0.f, a3 = 0.f;
        for (int i = 0; i < 16; ++i) {
            int tp = wave * 16 + i;
            float w = el_lds[tp];
            float4 e4 = *(const float4*)&encB[(size_t)tp * 256 + lane * 4];
            a0 += w * e4.x; a1 += w * e4.y; a2 += w * e4.z; a3 += w * e4.w;
        }
        atomicAdd(&ctx_lds[lane * 4 + 0], a0);
        atomicAdd(&ctx_lds[lane * 4 + 1], a1);
        atomicAdd(&ctx_lds[lane * 4 + 2], a2);
        atomicAdd(&ctx_lds[lane * 4 + 3], a3);
        __syncthreads();

        float qp = 0.f;
        if (tid < 256) {
            float ctx = ctx_lds[tid] * __builtin_amdgcn_rcpf(S);
            qp = h_lds[tid] * Wvb[tid] + ctx * Wvb[256 + tid];
        }
        if (wave < 4) {
            #pragma unroll
            for (int mm = 32; mm >= 1; mm >>= 1) qp += __shfl_xor(qp, mm, 64);
            if (lane == 0) ya[wave] = qp;
        }
        __syncthreads();
        if (tid < 256) {
            float qv = ya[0] + ya[1] + ya[2] + ya[3] + bvb[0];
            out[b * 256 + tid] = qv * Wwb[tid] + bwb[tid];
        }
    }
}

extern "C" void kernel_launch(void* const* d_in, const int* in_sizes, int n_in,
                              void* d_out, int out_size, void* d_ws, size_t ws_size,
                              hipStream_t stream) {
    const float* data = (const float*)d_in[0];
    const float* enc  = (const float*)d_in[1];
    const float* h0   = (const float*)d_in[2];
    const float* s0   = (const float*)d_in[3];
    const float* Wd   = (const float*)d_in[4];
    const float* bd   = (const float*)d_in[5];
    const float* Wk   = (const float*)d_in[6];
    const float* Wr   = (const float*)d_in[7];
    const float* bl   = (const float*)d_in[8];
    const float* Ww   = (const float*)d_in[9];
    const float* bw   = (const float*)d_in[10];
    const float* Wu   = (const float*)d_in[11];
    const float* bu   = (const float*)d_in[12];
    const float* Wv   = (const float*)d_in[13];
    const float* bv   = (const float*)d_in[14];
    const float* Wvb  = (const float*)d_in[15];
    const float* bvb  = (const float*)d_in[16];
    const float* Wwb  = (const float*)d_in[17];
    const float* bwb  = (const float*)d_in[18];

    _Float16* Ue16 = (_Float16*)d_ws;                                 // 32 MB
    uint4* Wsz  = (uint4*)((char*)d_ws + (32ull << 20));              // 512 KB
    uint4* Wwsz = (uint4*)((char*)d_ws + (32ull << 20) + (512ull << 10)); // 256 KB
    float* out = (float*)d_out;

    hipLaunchKernelGGL(ue_gemm, dim3((B * T) / 32), dim3(256), 0, stream,
                       enc, Wu, bu, Ue16);
    hipLaunchKernelGGL(wr_cvt, dim3(128), dim3(256), 0, stream, Wr, Wsz);
    hipLaunchKernelGGL(ww_cvt, dim3(64), dim3(256), 0, stream, Ww, Wwsz);
    hipLaunchKernelGGL(decoder_scan, dim3(B), dim3(NT), 0, stream,
                       data, h0, s0, Wd, bd, Wk, bl, bw,
                       Wv, bv, Wvb, bvb, Wwb, bwb,
                       enc, Ue16, Wsz, Wwsz, out);
}

// Round 10
// 2367.146 us; speedup vs baseline: 5.2679x; 1.1170x over previous
//
#include <hip/hip_runtime.h>
#include <hip/hip_bf16.h>

#define B 256
#define T 256
#define M 256
#define P 256
#define TSTEPS 255
#define NT 1024
#define RG 6      // G-resident Wr chunk-pairs (asm-pinned -> AGPR-parked)

typedef unsigned int uint;
typedef _Float16 hf2 __attribute__((ext_vector_type(2)));

#define KEEP4(v) asm volatile("" : "+v"((v).x), "+v"((v).y), "+v"((v).z), "+v"((v).w))

__device__ __forceinline__ float fast_tanh(float x) {
    float e = exp2f(x * 2.885390082f);             // e^(2x)
    return 1.f - 2.f * __builtin_amdgcn_rcpf(e + 1.f);
}
__device__ __forceinline__ float fast_sigmoid(float x) {
    float e = exp2f(-x * 1.442695041f);            // e^(-x)
    return __builtin_amdgcn_rcpf(1.f + e);
}

#if defined(__has_builtin)
#if __has_builtin(__builtin_amdgcn_fdot2)
#define HAVE_FDOT2 1
#endif
#endif

__device__ __forceinline__ float dot2(uint a, uint b, float c) {
#ifdef HAVE_FDOT2
    return __builtin_amdgcn_fdot2(__builtin_bit_cast(hf2, a),
                                  __builtin_bit_cast(hf2, b), c, false);
#else
    hf2 x = __builtin_bit_cast(hf2, a), y = __builtin_bit_cast(hf2, b);
    return c + (float)x.x * (float)y.x + (float)x.y * (float)y.y;
#endif
}

__device__ __forceinline__ uint pk16(float a, float b) {
    return __builtin_bit_cast(uint, __builtin_amdgcn_cvt_pkrtz(a, b));
}

// packed (u*d)^2 in f16x2 — forced v_pk codegen
__device__ __forceinline__ uint pkmulsq(uint a, uint b) {
    uint p;
    asm("v_pk_mul_f16 %0, %1, %2\n\t"
        "v_pk_mul_f16 %0, %0, %0" : "=v"(p) : "v"(a), "v"(b));
    return p;
}

__device__ __forceinline__ float rcp1p(float x) {      // 1/(x+1), rcp(inf)=0
    return __builtin_amdgcn_rcpf(x + 1.f);
}

// ---------------- EU = f16(exp(encoder_h @ Wu + bu)) ----------------
__global__ __launch_bounds__(256) void ue_gemm(
    const float* __restrict__ enc, const float* __restrict__ Wu,
    const float* __restrict__ bu, _Float16* __restrict__ Ue16)
{
    __shared__ float At[32][256];
    const int r0 = blockIdx.x * 32;
    const int tid = threadIdx.x;

    #pragma unroll 4
    for (int i = 0; i < 32; ++i)
        At[i][tid] = enc[(size_t)(r0 + i) * 256 + tid];
    __syncthreads();

    float acc[32];
    #pragma unroll
    for (int r = 0; r < 32; ++r) acc[r] = 0.f;

    for (int k = 0; k < 256; k += 4) {
        float w0 = Wu[(size_t)(k + 0) * 256 + tid];
        float w1 = Wu[(size_t)(k + 1) * 256 + tid];
        float w2 = Wu[(size_t)(k + 2) * 256 + tid];
        float w3 = Wu[(size_t)(k + 3) * 256 + tid];
        #pragma unroll
        for (int r = 0; r < 32; ++r) {
            float4 a4 = *(const float4*)&At[r][k];
            acc[r] += a4.x * w0 + a4.y * w1 + a4.z * w2 + a4.w * w3;
        }
    }
    float bub = bu[tid];
    #pragma unroll 4
    for (int r = 0; r < 32; ++r)
        Ue16[(size_t)(r0 + r) * 256 + tid] =
            (_Float16)exp2f(1.442695041f * (acc[r] + bub));   // e^{u}
}

// ---- Wsz[kc*1024+c] = uint4 of f16 pairs of Wr[kc*8+j][c], j=0..7 ----
__global__ __launch_bounds__(256) void wr_cvt(
    const float* __restrict__ Wr, uint4* __restrict__ Wsz)
{
    int i = blockIdx.x * 256 + threadIdx.x;        // 32768
    int kc = i >> 10, c = i & 1023;
    const float* s = Wr + (size_t)kc * 8 * 1024 + c;
    uint4 o;
    o.x = pk16(s[0 * 1024], s[1 * 1024]);
    o.y = pk16(s[2 * 1024], s[3 * 1024]);
    o.z = pk16(s[4 * 1024], s[5 * 1024]);
    o.w = pk16(s[6 * 1024], s[7 * 1024]);
    Wsz[i] = o;
}

// ---- Wwsz[kk*256+m] = uint4 of f16 pairs of Ww[kk*8+j][m], j=0..7 ----
__global__ __launch_bounds__(256) void ww_cvt(
    const float* __restrict__ Ww, uint4* __restrict__ Wwsz)
{
    int i = blockIdx.x * 256 + threadIdx.x;        // 16384
    int kk = i >> 8, m = i & 255;
    const float* s = Ww + (size_t)kk * 8 * 256 + m;
    uint4 o;
    o.x = pk16(s[0 * 256], s[1 * 256]);
    o.y = pk16(s[2 * 256], s[3 * 256]);
    o.z = pk16(s[4 * 256], s[5 * 256]);
    o.w = pk16(s[6 * 256], s[7 * 256]);
    Wwsz[i] = o;
}

// ---------------- main scan: one block (1024 thr) per batch element ----------------
__global__ __launch_bounds__(NT, 4) void decoder_scan(
    const float* __restrict__ data,
    const float* __restrict__ h0,  const float* __restrict__ s0,
    const float* __restrict__ Wd,  const float* __restrict__ bd,
    const float* __restrict__ Wk,  const float* __restrict__ bl,
    const float* __restrict__ bw,
    const float* __restrict__ Wv,  const float* __restrict__ bv,
    const float* __restrict__ Wvb, const float* __restrict__ bvb,
    const float* __restrict__ Wwb, const float* __restrict__ bwb,
    const float* __restrict__ enc,
    const _Float16* __restrict__ Ue16g,
    const uint4* __restrict__ Wsz, const uint4* __restrict__ Wwsz,
    float* __restrict__ out)
{
    const int b    = blockIdx.x;
    const int tid  = threadIdx.x;
    const int lane = tid & 63;
    const int wave = tid >> 6;          // 0..15

    __shared__ __align__(16) uint4 ww_lds[2 * 16 * 256];   // 128 KB, wave-linear layout
    __shared__ float h_lds[P], s_lds[P];
    __shared__ __align__(16) uint hs2[128 + 4 + 128];      // h2 @0, s2 @132
    __shared__ float z_lds[4 * 257];
    __shared__ __align__(16) uint  edup[2][132];           // ED f16 pairs, dup copies
    __shared__ __align__(16) float wv2dup[2][264];         // 2*Wv f32, dup copies
    __shared__ float el_lds[T];
    __shared__ float g_lds[T];
    __shared__ float ctx_lds[M];
    __shared__ __align__(16) float sred[8], yred[8];
    __shared__ float ya[4];
    __shared__ float data_lds[TSTEPS + 1];
    __shared__ int aflag;

    uint* h2_lds = hs2;
    uint* s2_lds = hs2 + 132;

    // ---- stage Ww halves into LDS: ww_lds[(i<<9)+(dm<<1)+dkh] = Wwsz[((dkh*32+i)<<8)+dm]
    {
        #pragma unroll
        for (int k = 0; k < 8; ++k) {
            int l = tid + k * NT;                  // 0..8191
            int i = l >> 9, r = l & 511, dmm = r >> 1, dk = r & 1;
            ww_lds[l] = Wwsz[((dk * 32 + i) << 8) + dmm];
        }
    }
    if (tid == 0) aflag = 0;
    if (tid < 256) {
        float hv = h0[b * 256 + tid], sv = s0[b * 256 + tid];
        h_lds[tid] = hv; s_lds[tid] = sv; ctx_lds[tid] = 0.f;
        float w2 = 2.f * Wv[tid];
        wv2dup[0][tid] = w2; wv2dup[1][tid] = w2;
        float hv1 = __shfl_down(hv, 1, 64);
        float sv1 = __shfl_down(sv, 1, 64);
        if (!(tid & 1)) {
            h2_lds[tid >> 1] = pk16(hv, hv1);
            s2_lds[tid >> 1] = pk16(sv, sv1);
        }
    }
    if (tid < 8) { sred[tid] = 1.f; yred[tid] = 0.f; }   // ctx_0 = 0
    if (tid < TSTEPS) data_lds[tid] = data[b * TSTEPS + tid];

    const float Wd0 = Wd[0], bd0 = bd[0];
    const float* encB = enc + (size_t)b * T * M;

    // ---- g[tp] = <enc[tp,:], Wd[1:]> ----
    {
        float w0 = Wd[1 + lane * 4], w1 = Wd[2 + lane * 4];
        float w2 = Wd[3 + lane * 4], w3 = Wd[4 + lane * 4];
        for (int i = 0; i < 16; ++i) {
            int tp = wave * 16 + i;
            float4 e4 = *(const float4*)&encB[(size_t)tp * 256 + lane * 4];
            float p = e4.x * w0 + e4.y * w1 + e4.z * w2 + e4.w * w3;
            #pragma unroll
            for (int mm = 32; mm >= 1; mm >>= 1) p += __shfl_xor(p, mm, 64);
            if (lane == 0) g_lds[tp] = p;
        }
    }
    __syncthreads();

    const uint4* h2u4 = (const uint4*)h2_lds;
    const uint4* s2u4 = (const uint4*)s2_lds;

    // ---- prologue: acc_0 = Wr·h_0 (all threads, 1 col each) ----
    {
        const uint4* wc = Wsz + tid;
        float acc = 0.f;
        #pragma unroll 4
        for (int kc = 0; kc < 32; ++kc) {
            uint4 w = wc[kc << 10];
            uint4 h = h2u4[kc];
            acc = dot2(w.x, h.x, acc); acc = dot2(w.y, h.y, acc);
            acc = dot2(w.z, h.z, acc); acc = dot2(w.w, h.w, acc);
        }
        z_lds[(tid >> 8) * 257 + (tid & 255)] = acc;
    }
    __syncthreads();

    if (wave < 8) {
        // ================= G-path (512 threads) =================
        const int gate = tid & 3, uu0 = tid >> 2, uu1 = uu0 + 128;
        const int cz0 = gate * 257 + uu0, cz1 = gate * 257 + uu1;
        const float wk0 = Wk[gate * 256 + uu0], bl0 = bl[gate * 256 + uu0];
        const float wk1 = Wk[gate * 256 + uu1], bl1 = bl[gate * 256 + uu1];
        const int zr = tid >> 8, zc = tid & 255;
        const uint4* wcA = Wsz + tid;
        const uint4* wcB = Wsz + tid + 512;
        uint4 rA[RG], rB[RG];
        #pragma unroll
        for (int kc = 0; kc < RG; ++kc) {
            rA[kc] = wcA[kc << 10]; rB[kc] = wcB[kc << 10];
            KEEP4(rA[kc]); KEEP4(rB[kc]);
        }

        for (int t = 0; t < TSTEPS; ++t) {
            // ---- P1: ys; gates for 2 columns; write h,s,h2,s2 ----
            {
                float4 sa = *(const float4*)&sred[0], sb = *(const float4*)&sred[4];
                float4 yaa = *(const float4*)&yred[0], yab = *(const float4*)&yred[4];
                float S = sa.x + sa.y + sa.z + sa.w + sb.x + sb.y + sb.z + sb.w;
                float Y = yaa.x + yaa.y + yaa.z + yaa.w + yab.x + yab.y + yab.z + yab.w;
                float ys = Y * __builtin_amdgcn_rcpf(S) + data_lds[t] * Wd0 + bd0;
                float zc0 = z_lds[cz0] + ys * wk0 + bl0;
                float zc1 = z_lds[cz1] + ys * wk1 + bl1;
                float nl0 = (gate == 2) ? fast_tanh(zc0) : fast_sigmoid(zc0);
                float nl1 = (gate == 2) ? fast_tanh(zc1) : fast_sigmoid(zc1);
                float a1 = __shfl_xor(nl0, 1, 64);
                float a2 = __shfl_xor(nl0, 2, 64);
                float a3 = __shfl_xor(nl0, 3, 64);
                float b1 = __shfl_xor(nl1, 1, 64);
                float b2 = __shfl_xor(nl1, 2, 64);
                float b3 = __shfl_xor(nl1, 3, 64);
                float hn0 = 0.f, sv0 = 0.f, hn1 = 0.f, sv1 = 0.f;
                if (gate == 0) {            // nl=sig_i a1=sig_f a2=tanh_g a3=sig_o
                    sv0 = a1 * s_lds[uu0] + nl0 * a2;
                    hn0 = a3 * fast_tanh(sv0);
                    sv1 = b1 * s_lds[uu1] + nl1 * b2;
                    hn1 = b3 * fast_tanh(sv1);
                    s_lds[uu0] = sv0; h_lds[uu0] = hn0;
                    s_lds[uu1] = sv1; h_lds[uu1] = hn1;
                }
                float hd0 = __shfl_down(hn0, 4, 64), sd0 = __shfl_down(sv0, 4, 64);
                float hd1 = __shfl_down(hn1, 4, 64), sd1 = __shfl_down(sv1, 4, 64);
                if ((tid & 7) == 0) {
                    h2_lds[uu0 >> 1] = pk16(hn0, hd0); s2_lds[uu0 >> 1] = pk16(sv0, sd0);
                    h2_lds[uu1 >> 1] = pk16(hn1, hd1); s2_lds[uu1 >> 1] = pk16(sv1, sd1);
                }
            }
            __syncthreads();                         // X: h_{t+1} ready

            float a0 = 0.f, a1 = 0.f;
            #pragma unroll
            for (int kc = 0; kc < RG; ++kc) {        // reg-resident: pure VALU
                uint4 h = h2u4[kc];
                a0 = dot2(rA[kc].x, h.x, a0); a0 = dot2(rA[kc].y, h.y, a0);
                a0 = dot2(rA[kc].z, h.z, a0); a0 = dot2(rA[kc].w, h.w, a0);
                a1 = dot2(rB[kc].x, h.x, a1); a1 = dot2(rB[kc].y, h.y, a1);
                a1 = dot2(rB[kc].z, h.z, a1); a1 = dot2(rB[kc].w, h.w, a1);
            }
            #pragma unroll 4
            for (int kc = RG; kc < 32; ++kc) {       // streamed from L2
                uint4 wA = wcA[kc << 10], wB = wcB[kc << 10];
                uint4 h = h2u4[kc];
                a0 = dot2(wA.x, h.x, a0); a0 = dot2(wA.y, h.y, a0);
                a0 = dot2(wA.z, h.z, a0); a0 = dot2(wA.w, h.w, a0);
                a1 = dot2(wB.x, h.x, a1); a1 = dot2(wB.y, h.y, a1);
                a1 = dot2(wB.z, h.z, a1); a1 = dot2(wB.w, h.w, a1);
            }
            z_lds[zr * 257 + zc] = a0;
            z_lds[(2 + zr) * 257 + zc] = a1;
            __syncthreads();                         // Z
        }
    } else {
        // ================= A-path (512 threads) =================
        const int aw  = wave - 8;
        const int aid = tid - 512;
        const int dm  = aid >> 1;                   // D: m-col / E: row
        const int dkh = aid & 1;                    // D: K-half, E: m-half
        const float bwm = bw[dm];
        const uint4* wwp  = Wwsz + (dkh << 13) + dm;        // global stream, kk=dkh*32+i
        const uint4* wwl  = ww_lds + aid;                   // LDS, wave-linear
        const uint4*  edT = (const uint4*)(&edup[dkh][0]) + (dkh << 4);
        const float4* wvT = (const float4*)(&wv2dup[dkh][0]) + (dkh << 5);
        const uint4* cat4 = dkh ? s2u4 : h2u4;

        // ---- EU row-half into registers (64 regs, pinned) ----
        uint4 eu[16];
        {
            const uint4* eusrc = (const uint4*)(Ue16g + (size_t)b * T * M) + (aid << 4);
            #pragma unroll
            for (int i = 0; i < 16; ++i) { eu[i] = eusrc[i]; KEEP4(eu[i]); }
        }

        for (int t = 0; t < TSTEPS; ++t) {
            __syncthreads();                         // X: h2/s2 ready
            // ---- D: dsc column dm, K-half dkh: 16 LDS chunks + 16 streamed ----
            float a = 0.f;
            #pragma unroll 4
            for (int i = 0; i < 16; ++i) {
                uint4 w = wwl[i << 9];
                uint4 c = cat4[i];
                a = dot2(w.x, c.x, a); a = dot2(w.y, c.y, a);
                a = dot2(w.z, c.z, a); a = dot2(w.w, c.w, a);
            }
            #pragma unroll 4
            for (int i = 16; i < 32; ++i) {
                uint4 w = wwp[i << 8];
                uint4 c = cat4[i];
                a = dot2(w.x, c.x, a); a = dot2(w.y, c.y, a);
                a = dot2(w.z, c.z, a); a = dot2(w.w, c.w, a);
            }
            a += __shfl_xor(a, 1, 64);               // merge K-halves
            float ed = exp2f(1.442695041f * (a + bwm));   // e^{dsc}
            float ed2 = __shfl_xor(ed, 2, 64);            // partner m+1
            if ((aid & 3) == 0) {
                uint u = pk16(ed, ed2);
                edup[0][dm >> 1] = u;
                edup[1][dm >> 1] = u;
            }
            // ---- A-internal sync: all ED written ----
            __threadfence_block();
            if (lane == 0) atomicAdd(&aflag, 1);
            const int tgt = 8 * (t + 1);
            while (*(volatile int*)&aflag < tgt) __builtin_amdgcn_s_sleep(1);
            __threadfence_block();

            // ---- E: per-element rcp form (EU in regs) ----
            __builtin_amdgcn_s_setprio(1);
            float pl = 0.f;                          // Σ 2wv / (q+1), q=(eu·ed)²
            #pragma unroll
            for (int jj = 0; jj < 16; ++jj) {
                uint4 u = eu[jj];
                uint4 d = edT[jj];
                float4 wA = wvT[jj * 2], wB = wvT[jj * 2 + 1];
                uint q0 = pkmulsq(u.x, d.x);
                uint q1 = pkmulsq(u.y, d.y);
                uint q2 = pkmulsq(u.z, d.z);
                uint q3 = pkmulsq(u.w, d.w);
                hf2 g0 = __builtin_bit_cast(hf2, q0);
                hf2 g1 = __builtin_bit_cast(hf2, q1);
                hf2 g2 = __builtin_bit_cast(hf2, q2);
                hf2 g3 = __builtin_bit_cast(hf2, q3);
                pl = fmaf(wA.x, rcp1p((float)g0.x), pl);
                pl = fmaf(wA.y, rcp1p((float)g0.y), pl);
                pl = fmaf(wA.z, rcp1p((float)g1.x), pl);
                pl = fmaf(wA.w, rcp1p((float)g1.y), pl);
                pl = fmaf(wB.x, rcp1p((float)g2.x), pl);
                pl = fmaf(wB.y, rcp1p((float)g2.y), pl);
                pl = fmaf(wB.z, rcp1p((float)g3.x), pl);
                pl = fmaf(wB.w, rcp1p((float)g3.y), pl);
            }
            pl += __shfl_xor(pl, 1, 64);             // merge m-halves
            float ev = exp2f(-1.442695041f * pl);    // softmax const dropped
            if (!dkh) el_lds[dm] = ev;
            float yg = ev * g_lds[dm];
            #pragma unroll
            for (int mm = 2; mm <= 32; mm <<= 1) {
                ev += __shfl_xor(ev, mm, 64);
                yg += __shfl_xor(yg, mm, 64);
            }
            if (lane == 0) { sred[aw] = ev; yred[aw] = yg; }
            __builtin_amdgcn_s_setprio(0);
            __syncthreads();                         // Z
        }
    }

    // ---- epilogue: final ctx from el(254) + fp32 enc, then output head ----
    {
        float S;
        {
            float4 sa = *(const float4*)&sred[0], sb = *(const float4*)&sred[4];
            S = sa.x + sa.y + sa.z + sa.w + sb.x + sb.y + sb.z + sb.w;
        }
        float a0 = 0.f, a1 = 0.f, a2 = 0.f, a3 = 0.f;
        for (int i = 0; i < 16; ++i) {
            int tp = wave * 16 + i;
            float w = el_lds[tp];
            float4 e4 = *(const float4*)&encB[(size_t)tp * 256 + lane * 4];
            a0 += w * e4.x; a1 += w * e4.y; a2 += w * e4.z; a3 += w * e4.w;
        }
        atomicAdd(&ctx_lds[lane * 4 + 0], a0);
        atomicAdd(&ctx_lds[lane * 4 + 1], a1);
        atomicAdd(&ctx_lds[lane * 4 + 2], a2);
        atomicAdd(&ctx_lds[lane * 4 + 3], a3);
        __syncthreads();

        float qp = 0.f;
        if (tid < 256) {
            float ctx = ctx_lds[tid] * __builtin_amdgcn_rcpf(S);
            qp = h_lds[tid] * Wvb[tid] + ctx * Wvb[256 + tid];
        }
        if (wave < 4) {
            #pragma unroll
            for (int mm = 32; mm >= 1; mm >>= 1) qp += __shfl_xor(qp, mm, 64);
            if (lane == 0) ya[wave] = qp;
        }
        __syncthreads();
        if (tid < 256) {
            float qv = ya[0] + ya[1] + ya[2] + ya[3] + bvb[0];
            out[b * 256 + tid] = qv * Wwb[tid] + bwb[tid];
        }
    }
}

extern "C" void kernel_launch(void* const* d_in, const int* in_sizes, int n_in,
                              void* d_out, int out_size, void* d_ws, size_t ws_size,
                              hipStream_t stream) {
    const float* data = (const float*)d_in[0];
    const float* enc  = (const float*)d_in[1];
    const float* h0   = (const float*)d_in[2];
    const float* s0   = (const float*)d_in[3];
    const float* Wd   = (const float*)d_in[4];
    const float* bd   = (const float*)d_in[5];
    const float* Wk   = (const float*)d_in[6];
    const float* Wr   = (const float*)d_in[7];
    const float* bl   = (const float*)d_in[8];
    const float* Ww   = (const float*)d_in[9];
    const float* bw   = (const float*)d_in[10];
    const float* Wu   = (const float*)d_in[11];
    const float* bu   = (const float*)d_in[12];
    const float* Wv   = (const float*)d_in[13];
    const float* bv   = (const float*)d_in[14];
    const float* Wvb  = (const float*)d_in[15];
    const float* bvb  = (const float*)d_in[16];
    const float* Wwb  = (const float*)d_in[17];
    const float* bwb  = (const float*)d_in[18];

    _Float16* Ue16 = (_Float16*)d_ws;                                 // 32 MB
    uint4* Wsz  = (uint4*)((char*)d_ws + (32ull << 20));              // 512 KB
    uint4* Wwsz = (uint4*)((char*)d_ws + (32ull << 20) + (512ull << 10)); // 256 KB
    float* out = (float*)d_out;

    hipLaunchKernelGGL(ue_gemm, dim3((B * T) / 32), dim3(256), 0, stream,
                       enc, Wu, bu, Ue16);
    hipLaunchKernelGGL(wr_cvt, dim3(128), dim3(256), 0, stream, Wr, Wsz);
    hipLaunchKernelGGL(ww_cvt, dim3(64), dim3(256), 0, stream, Ww, Wwsz);
    hipLaunchKernelGGL(decoder_scan, dim3(B), dim3(NT), 0, stream,
                       data, h0, s0, Wd, bd, Wk, bl, bw,
                       Wv, bv, Wvb, bvb, Wwb, bwb,
                       enc, Ue16, Wsz, Wwsz, out);
}